// Round 11
// baseline (669.682 us; speedup 1.0000x reference)
//
#include <hip/hip_runtime.h>
#include <math.h>

#define NPIX 4096
#define CC   256

typedef __attribute__((ext_vector_type(8))) short bf16x8;
typedef __attribute__((ext_vector_type(4))) float f32x4;

__device__ inline unsigned short f2bf(float f) {
    unsigned u = __builtin_bit_cast(unsigned, f);
    u += 0x7FFF + ((u >> 16) & 1);              // RTN-E
    return (unsigned short)(u >> 16);
}
__device__ inline float bf2f(unsigned short h) {
    unsigned u = (unsigned)h << 16;
    return __builtin_bit_cast(float, u);
}
__device__ inline void gl_lds16(const void* g, void* l) {
    __builtin_amdgcn_global_load_lds(
        (const __attribute__((address_space(1))) void*)g,
        (__attribute__((address_space(3))) void*)l, 16, 0, 0);
}

// ---------------------------------------------------------------------------
// Weight prep (unchanged, verified)
// ---------------------------------------------------------------------------
__global__ __launch_bounds__(256) void prep_kernel(
    const float* __restrict__ w2, const float* __restrict__ w3,
    const float* __restrict__ wq, const float* __restrict__ wk,
    const float* __restrict__ wv, const float* __restrict__ wb1,
    const float* __restrict__ wb2, const float* __restrict__ bq,
    const float* __restrict__ bk,
    unsigned short* w2b, unsigned short* w3b, unsigned short* wqb,
    unsigned short* wkb, unsigned short* wvb,
    unsigned short* wr1, unsigned short* wr2, float* bqk) {
    int i = blockIdx.x * 256 + threadIdx.x;
    if (i < 8192)  w2b[i] = f2bf(w2[i]);
    if (i < 32768) w3b[i] = f2bf(w3[i]);
    if (i < 65536) { wqb[i] = f2bf(wq[i]); wkb[i] = f2bf(wk[i]); wvb[i] = f2bf(wv[i]); }
    if (i < 256)   { bqk[i] = bq[i]; bqk[256 + i] = bk[i]; }
    if (i < 589824) {
        int o = i / 2304; int r = i - o * 2304; int tap = r >> 8; int c = r & 255;
        wr1[i] = f2bf(wb1[(o * 256 + c) * 9 + tap]);
        wr2[i] = f2bf(wb2[(o * 256 + c) * 9 + tap]);
    }
}

// ---------------------------------------------------------------------------
// Stem (unchanged, verified)
// ---------------------------------------------------------------------------
__global__ __launch_bounds__(256) void stem1_kernel(
    const float* __restrict__ x, const float* __restrict__ w1,
    const float* __restrict__ b1, unsigned short* __restrict__ h1T) {
    int idx = blockIdx.x * 256 + threadIdx.x;
    int o = idx & 63;
    int p = (idx >> 6) & 4095;
    int b = idx >> 18;
    const float* xb = x + (size_t)b * 3 * NPIX + p;
    float acc = b1[o];
    acc = fmaf(w1[o * 3 + 0], xb[0],        acc);
    acc = fmaf(w1[o * 3 + 1], xb[NPIX],     acc);
    acc = fmaf(w1[o * 3 + 2], xb[2 * NPIX], acc);
    h1T[idx] = f2bf(fmaxf(acc, 0.f));
}

// ---------------------------------------------------------------------------
// Full-K single-stage GEMM (K<=256) — verified. conv2/conv3 1x1, q|k, V'.
// EPI 1: bf16 +bias[col] relu; 2: bf16 +bias[col];
// EPI 3: bf16 (acc+bias[row]) * aux[z*4096+col]   (V' scaled by 1/D[n])
// ---------------------------------------------------------------------------
template<int EPI, int KK>
__global__ __launch_bounds__(256) void gemm_fullk(
    const unsigned short* __restrict__ A, long lda, long sA,
    const unsigned short* __restrict__ BT, long ldb, long sB,
    void* __restrict__ Cp, long ldc, long sC,
    const float* __restrict__ bias, float* __restrict__ aux) {
    constexpr int SPR = KK / 8;
    constexpr int RPI = 64 / SPR;
    __shared__ unsigned short As[128 * KK];
    __shared__ unsigned short Bs[128 * KK];
    const int tid  = threadIdx.x;
    const int lane = tid & 63;
    const int wave = tid >> 6;
    const int wr = (wave >> 1) * 64, wc = (wave & 1) * 64;
    const int l15 = lane & 15, lh = lane >> 4;
    const int sl  = lane & (SPR - 1);
    const int rof = lane / SPR;
    const int z = blockIdx.z;
    const unsigned short* Ab = A  + (size_t)z * sA + (size_t)blockIdx.y * 128 * lda;
    const unsigned short* Bb = BT + (size_t)z * sB + (size_t)blockIdx.x * 128 * ldb;

    f32x4 acc[4][4];
    #pragma unroll
    for (int i = 0; i < 4; ++i)
        #pragma unroll
        for (int j = 0; j < 4; ++j) { f32x4 zr = {0.f, 0.f, 0.f, 0.f}; acc[i][j] = zr; }

    #pragma unroll
    for (int i = 0; i < KK / 16; ++i) {
        int r0  = wave * 32 + i * RPI;
        int row = r0 + rof;
        int cs  = (sl ^ (row & (SPR - 1))) * 8;
        gl_lds16(Ab + (size_t)row * lda + cs, &As[r0 * KK]);
        gl_lds16(Bb + (size_t)row * ldb + cs, &Bs[r0 * KK]);
    }
    __syncthreads();

    #pragma unroll
    for (int ks = 0; ks < KK / 32; ++ks) {
        bf16x8 a[4], b[4];
        #pragma unroll
        for (int f = 0; f < 4; ++f) {
            int ra = wr + f * 16 + l15;
            a[f] = *(const bf16x8*)&As[ra * KK + ((((ks << 2) + lh) ^ (ra & (SPR - 1))) << 3)];
            int rb = wc + f * 16 + l15;
            b[f] = *(const bf16x8*)&Bs[rb * KK + ((((ks << 2) + lh) ^ (rb & (SPR - 1))) << 3)];
        }
        #pragma unroll
        for (int i = 0; i < 4; ++i)
            #pragma unroll
            for (int j = 0; j < 4; ++j)
                acc[i][j] = __builtin_amdgcn_mfma_f32_16x16x32_bf16(
                    a[i], b[j], acc[i][j], 0, 0, 0);
    }

    const int row0 = blockIdx.y * 128 + wr;
    const int col0 = blockIdx.x * 128 + wc;
    unsigned short* OUT = (unsigned short*)Cp + (size_t)z * sC;
    #pragma unroll
    for (int i = 0; i < 4; ++i)
        #pragma unroll
        for (int j = 0; j < 4; ++j) {
            int cgl = col0 + j * 16 + l15;
            float bc = (EPI == 1 || EPI == 2) ? bias[cgl] : 0.f;
            float sc = (EPI == 3) ? aux[(size_t)z * 4096 + cgl] : 1.f;
            #pragma unroll
            for (int q = 0; q < 4; ++q) {
                int r = row0 + i * 16 + lh * 4 + q;
                float v = acc[i][j][q];
                if (EPI == 3) v = (v + bias[r]) * sc;
                else v += bc;
                if (EPI == 1) v = fmaxf(v, 0.f);
                OUT[(size_t)r * ldc + cgl] = f2bf(v);
            }
        }
}

// ---------------------------------------------------------------------------
// 256x256-tile GEMM, 8 waves, BK=32 -> 64 KB LDS -> 2 blocks/CU (the round-10
// lesson: 1-block/CU occupancy was the invariant binder across 3 schedules).
// Counted-vmcnt 2-phase pipeline (verified R8). Swizzle: slot ^= (row>>1)&3
// on global source AND fragment read (involution, <=2-way banks).
// __launch_bounds__(512,4) pins VGPR<=128 so occupancy is LDS-limited.
// EPI 0: S — store bf16(exp(acc)) + column-sum partials -> aux
// EPI 4: PV — split-K; splits==1: alpha*CV+beta*acc; else bf16 partials
// ---------------------------------------------------------------------------
template<int EPI>
__global__ __launch_bounds__(512, 4) void gemm256(
    const unsigned short* __restrict__ A, long lda, long sA,
    const unsigned short* __restrict__ BT, long ldb, long sB,
    int Kc, int splits, int nb,
    void* __restrict__ Cp, long ldc, long sC,
    float* __restrict__ aux, unsigned short* __restrict__ partial,
    const unsigned short* __restrict__ CV,
    const float* __restrict__ alphaP, const float* __restrict__ betaP,
    int nwgc) {
    __shared__ unsigned short As[2][256 * 32];
    __shared__ unsigned short Bs[2][256 * 32];
    const int orig = blockIdx.x;
    const int wgid = (orig & 7) * nwgc + (orig >> 3);    // XCD-chunked, bijective
    int bx, by, sp, z;
    if (EPI == 0) { bx = wgid & 15; by = (wgid >> 4) & 15; z = wgid >> 8; sp = 0; }
    else          { bx = wgid & 15; sp = (wgid >> 4) % splits; z = wgid / (16 * splits); by = 0; }

    const int tid  = threadIdx.x;
    const int lane = tid & 63;
    const int wave = tid >> 6;
    const int wr = (wave >> 2) * 128;       // row half
    const int wc = (wave & 3) * 64;         // col quarter
    const int l15 = lane & 15, lh = lane >> 4;
    const int srow = lane >> 2, sslot = lane & 3;
    const unsigned short* Ab = A  + (size_t)z * sA + (size_t)by * 256 * lda + (size_t)sp * Kc;
    const unsigned short* Bb = BT + (size_t)z * sB + (size_t)bx * 256 * ldb + (size_t)sp * Kc;

    f32x4 acc[8][4];
    #pragma unroll
    for (int i = 0; i < 8; ++i)
        #pragma unroll
        for (int j = 0; j < 4; ++j) { f32x4 zr = {0.f, 0.f, 0.f, 0.f}; acc[i][j] = zr; }

    auto STAGE = [&](int buf, int k0) {       // 4 gl_lds per wave (2 A + 2 B)
        #pragma unroll
        for (int s = 0; s < 2; ++s) {
            int rb  = wave * 32 + s * 16;
            int row = rb + srow;
            int cs  = (sslot ^ ((row >> 1) & 3)) * 8;
            gl_lds16(Ab + (size_t)row * lda + k0 + cs, &As[buf][rb * 32]);
            gl_lds16(Bb + (size_t)row * ldb + k0 + cs, &Bs[buf][rb * 32]);
        }
    };

    STAGE(0, 0);
    const int T = Kc >> 5;
    for (int t = 0; t < T; ++t) {
        const int cur = t & 1;
        if (t + 1 < T) {
            STAGE(cur ^ 1, (t + 1) << 5);     // next tile: stays in flight
            asm volatile("s_waitcnt vmcnt(4)" ::: "memory");   // tile t landed
        } else {
            asm volatile("s_waitcnt vmcnt(0)" ::: "memory");
        }
        __builtin_amdgcn_s_barrier();
        asm volatile("" ::: "memory");
        __builtin_amdgcn_s_setprio(1);
        {
            bf16x8 a[8], b[4];
            #pragma unroll
            for (int f = 0; f < 8; ++f) {
                int ra = wr + f * 16 + l15;
                a[f] = *(const bf16x8*)&As[cur][ra * 32 + ((lh ^ ((ra >> 1) & 3)) << 3)];
            }
            #pragma unroll
            for (int f = 0; f < 4; ++f) {
                int rb = wc + f * 16 + l15;
                b[f] = *(const bf16x8*)&Bs[cur][rb * 32 + ((lh ^ ((rb >> 1) & 3)) << 3)];
            }
            #pragma unroll
            for (int i = 0; i < 8; ++i)
                #pragma unroll
                for (int j = 0; j < 4; ++j)
                    acc[i][j] = __builtin_amdgcn_mfma_f32_16x16x32_bf16(
                        a[i], b[j], acc[i][j], 0, 0, 0);
        }
        __builtin_amdgcn_s_setprio(0);
        asm volatile("" ::: "memory");
        __builtin_amdgcn_s_barrier();
    }

    if (EPI == 0) {
        unsigned short* OUT = (unsigned short*)Cp + (size_t)z * sC;
        const int row0 = by * 256 + wr;
        const int col0 = bx * 256 + wc;
        float cs4[4] = {0.f, 0.f, 0.f, 0.f};
        #pragma unroll
        for (int i = 0; i < 8; ++i)
            #pragma unroll
            for (int j = 0; j < 4; ++j) {
                int cgl = col0 + j * 16 + l15;
                #pragma unroll
                for (int q = 0; q < 4; ++q) {
                    int r = row0 + i * 16 + lh * 4 + q;
                    unsigned short h = f2bf(__expf(acc[i][j][q]));
                    OUT[(size_t)r * ldc + cgl] = h;
                    cs4[j] += bf2f(h);          // sum the ROUNDED numerator
                }
            }
        #pragma unroll
        for (int off = 16; off <= 32; off <<= 1)
            #pragma unroll
            for (int j = 0; j < 4; ++j)
                cs4[j] += __shfl_xor(cs4[j], off);
        if (lh == 0) {
            float* part = aux + (((size_t)z * 16 + by) * 2 + (wave >> 2)) * 4096;
            #pragma unroll
            for (int j = 0; j < 4; ++j)
                part[col0 + j * 16 + l15] = cs4[j];
        }
    } else {
        const int col0 = bx * 256 + wc;
        if (splits == 1) {
            float* OUT = (float*)Cp + (size_t)z * sC;
            const unsigned short* CVb = CV + (size_t)z * sC;
            const float al = alphaP[0], be = betaP[0];
            #pragma unroll
            for (int i = 0; i < 8; ++i)
                #pragma unroll
                for (int j = 0; j < 4; ++j) {
                    int cgl = col0 + j * 16 + l15;
                    #pragma unroll
                    for (int q = 0; q < 4; ++q) {
                        int r = wr + i * 16 + lh * 4 + q;
                        size_t o = (size_t)r * ldc + cgl;
                        OUT[o] = al * bf2f(CVb[o]) + be * acc[i][j][q];
                    }
                }
        } else {
            unsigned short* P = partial + ((size_t)sp * nb + z) * ((size_t)256 * 4096);
            #pragma unroll
            for (int i = 0; i < 8; ++i)
                #pragma unroll
                for (int j = 0; j < 4; ++j) {
                    int cgl = col0 + j * 16 + l15;
                    #pragma unroll
                    for (int q = 0; q < 4; ++q) {
                        int r = wr + i * 16 + lh * 4 + q;
                        P[(size_t)r * 4096 + cgl] = f2bf(acc[i][j][q]);
                    }
                }
        }
    }
}

// ---------------------------------------------------------------------------
// reduce: out = alpha*cv + beta * sum_sp bf16partial[sp]
// ---------------------------------------------------------------------------
__global__ __launch_bounds__(256) void reduce_kernel(
    const unsigned short* __restrict__ partial, const unsigned short* __restrict__ cvb,
    const float* __restrict__ alphaP, const float* __restrict__ betaP,
    float* __restrict__ outp, int splits, long chunk) {
    long idx = ((long)blockIdx.x * 256 + threadIdx.x) * 4;
    if (idx >= chunk) return;
    float s0 = 0.f, s1 = 0.f, s2 = 0.f, s3 = 0.f;
    for (int sp = 0; sp < splits; ++sp) {
        ushort4 p = *(const ushort4*)&partial[(size_t)sp * chunk + idx];
        s0 += bf2f(p.x); s1 += bf2f(p.y); s2 += bf2f(p.z); s3 += bf2f(p.w);
    }
    ushort4 c4 = *(const ushort4*)&cvb[idx];
    const float al = alphaP[0], be = betaP[0];
    float4 r;
    r.x = al * bf2f(c4.x) + be * s0;
    r.y = al * bf2f(c4.y) + be * s1;
    r.z = al * bf2f(c4.z) + be * s2;
    r.w = al * bf2f(c4.w) + be * s3;
    *(float4*)&outp[idx] = r;
}

// ---------------------------------------------------------------------------
// rcp[z][n] = 1 / sum over 32 partials (16 row-blocks x 2 halves)
// ---------------------------------------------------------------------------
__global__ __launch_bounds__(256) void recip_kernel(
    const float* __restrict__ part, float* __restrict__ rcp) {
    int idx = blockIdx.x * 256 + threadIdx.x;
    int z = idx >> 12, n = idx & 4095;
    const float* pb = part + (size_t)z * 32 * 4096 + n;
    float s = 0.f;
    #pragma unroll 8
    for (int t = 0; t < 32; ++t) s += pb[(size_t)t * 4096];
    rcp[idx] = 1.f / s;
}

// ---------------------------------------------------------------------------
// 3x3 SAME conv v2 (unchanged, verified rounds 7-10)
// ---------------------------------------------------------------------------
template<int PIXOUT>
__global__ __launch_bounds__(256) void conv3_v2(
    const unsigned short* __restrict__ X, const unsigned short* __restrict__ Wr,
    const float* __restrict__ bias, void* __restrict__ Outp) {
    __shared__ unsigned short wt[9 * 128 * 40];
    __shared__ unsigned short patch[264 * 40];
    const int tid  = threadIdx.x;
    const int lane = tid & 63;
    const int wave = tid >> 6;
    const int l15 = lane & 15, lh = lane >> 4;
    const int oh = blockIdx.x & 1;
    const int b  = blockIdx.x >> 1;
    const int h0 = blockIdx.y;
    const int wy = (wave >> 1) * 64, wx = (wave & 1) * 64;
    const int obase = PIXOUT ? wx : wy;
    const int pbase = PIXOUT ? wy : wx;
    const unsigned short* Xb  = X + (size_t)b * (NPIX * CC);
    const unsigned short* Wro = Wr + (size_t)oh * 128 * 2304;

    f32x4 acc[4][4];
    #pragma unroll
    for (int i = 0; i < 4; ++i)
        #pragma unroll
        for (int j = 0; j < 4; ++j) { f32x4 zr = {0.f, 0.f, 0.f, 0.f}; acc[i][j] = zr; }

    for (int c0 = 0; c0 < 256; c0 += 32) {
        __syncthreads();
        #pragma unroll
        for (int t = 0; t < 5; ++t) {
            int q = t * 256 + tid;
            if (q < 1056) {
                int slot = q >> 2, cg = (q & 3) * 8;
                int r = slot / 66, w = slot - r * 66;
                int hh = h0 * 2 - 1 + r, ww = w - 1;
                int4 v = make_int4(0, 0, 0, 0);
                if ((unsigned)hh < 64u && (unsigned)ww < 64u)
                    v = *(const int4*)&Xb[(size_t)(hh * 64 + ww) * 256 + c0 + cg];
                *(int4*)&patch[slot * 40 + cg] = v;
            }
        }
        #pragma unroll
        for (int t = 0; t < 18; ++t) {
            int q = t * 256 + tid;
            int o = q / 36, rem = q - o * 36;
            int tap = rem >> 2, cg = (rem & 3) * 8;
            int4 v = *(const int4*)&Wro[(size_t)o * 2304 + tap * 256 + c0 + cg];
            *(int4*)&wt[(tap * 128 + o) * 40 + cg] = v;
        }
        __syncthreads();
        #pragma unroll
        for (int tap = 0; tap < 9; ++tap) {
            const int dy = tap / 3 - 1, dx = tap % 3 - 1;
            bf16x8 wf[4], pf[4];
            #pragma unroll
            for (int f = 0; f < 4; ++f) {
                int o = obase + f * 16 + l15;
                wf[f] = *(const bf16x8*)&wt[(tap * 128 + o) * 40 + lh * 8];
                int p = pbase + f * 16 + l15;
                int slot = ((p >> 6) + dy + 1) * 66 + (p & 63) + dx + 1;
                pf[f] = *(const bf16x8*)&patch[slot * 40 + lh * 8];
            }
            #pragma unroll
            for (int i = 0; i < 4; ++i)
                #pragma unroll
                for (int j = 0; j < 4; ++j) {
                    if (PIXOUT)
                        acc[i][j] = __builtin_amdgcn_mfma_f32_16x16x32_bf16(
                            pf[i], wf[j], acc[i][j], 0, 0, 0);
                    else
                        acc[i][j] = __builtin_amdgcn_mfma_f32_16x16x32_bf16(
                            wf[i], pf[j], acc[i][j], 0, 0, 0);
                }
        }
    }

    const int P0 = h0 * 128;
    if (PIXOUT) {
        unsigned short* O = (unsigned short*)Outp + (size_t)b * (NPIX * CC);
        #pragma unroll
        for (int i = 0; i < 4; ++i)
            #pragma unroll
            for (int j = 0; j < 4; ++j) {
                int o = oh * 128 + obase + j * 16 + l15;
                float bb = bias[o];
                #pragma unroll
                for (int q = 0; q < 4; ++q) {
                    int p = pbase + i * 16 + lh * 4 + q;
                    float v = fmaxf(acc[i][j][q] + bb, 0.f);
                    O[(size_t)(P0 + p) * CC + o] = f2bf(v);
                }
            }
    } else {
        unsigned short* O = (unsigned short*)Outp + (size_t)b * (CC * NPIX);
        #pragma unroll
        for (int i = 0; i < 4; ++i)
            #pragma unroll
            for (int j = 0; j < 4; ++j) {
                #pragma unroll
                for (int q = 0; q < 4; ++q) {
                    int o = oh * 128 + obase + i * 16 + lh * 4 + q;
                    int p = pbase + j * 16 + l15;
                    O[(size_t)o * NPIX + P0 + p] = f2bf(acc[i][j][q] + bias[o]);
                }
            }
    }
}

// ---------------------------------------------------------------------------
extern "C" void kernel_launch(void* const* d_in, const int* in_sizes, int n_in,
                              void* d_out, int out_size, void* d_ws, size_t ws_size,
                              hipStream_t stream) {
    const float* x   = (const float*)d_in[0];
    const float* w1  = (const float*)d_in[1];  const float* b1  = (const float*)d_in[2];
    const float* w2  = (const float*)d_in[3];  const float* b2  = (const float*)d_in[4];
    const float* w3  = (const float*)d_in[5];  const float* b3  = (const float*)d_in[6];
    const float* wb1 = (const float*)d_in[7];  const float* bb1 = (const float*)d_in[8];
    const float* wb2 = (const float*)d_in[9];  const float* bb2 = (const float*)d_in[10];
    const float* wq  = (const float*)d_in[11]; const float* bq  = (const float*)d_in[12];
    const float* wk  = (const float*)d_in[13]; const float* bk  = (const float*)d_in[14];
    const float* wv  = (const float*)d_in[15]; const float* bv  = (const float*)d_in[16];
    const float* alpha = (const float*)d_in[17];
    const float* beta  = (const float*)d_in[18];

    const size_t MB = 1 << 20;
    char* wsb = (char*)d_ws;
    unsigned short* x3T = (unsigned short*)(wsb + 0 * MB);   // [4][4096][256]
    unsigned short* qkT = (unsigned short*)(wsb + 8 * MB);   // [4][4096][512]
    unsigned short* cv  = (unsigned short*)(wsb + 24 * MB);  // [4][256][4096] bf16
    unsigned short* t1T = (unsigned short*)(wsb + 32 * MB);  // [4][4096][256]
    unsigned short* h1T = (unsigned short*)(wsb + 32 * MB);  // overlay
    unsigned short* h2T = (unsigned short*)(wsb + 34 * MB);  // overlay
    unsigned short* vB  = (unsigned short*)(wsb + 40 * MB);  // [nb][256][4096] bf16
    unsigned short* w2b = (unsigned short*)(wsb + 48 * MB);
    unsigned short* w3b = w2b + 8192;
    unsigned short* wqb = w3b + 32768;
    unsigned short* wkb = wqb + 65536;
    unsigned short* wvb = wkb + 65536;
    unsigned short* wr1 = wvb + 65536;
    unsigned short* wr2 = wr1 + 589824;
    float*          bqk  = (float*)(wsb + 51 * MB);
    float*          part = (float*)(wsb + 52 * MB);          // [nb][16][2][4096]
    float*          rcp  = (float*)(wsb + 54 * MB);          // [nb][4096]
    unsigned short* ST   = (unsigned short*)(wsb + 55 * MB); // [nb][4096][4096] bf16
    float* out = (float*)d_out;
    const long ONEM = (long)CC * NPIX;
    const long SS = 4096L * 4096;

    // PV grid = 16*splits*nb blocks; want >=512 (2/CU). bf16 partials =
    // splits*nb*2MB. Gates: nb=4,s=8 -> 55+128+64=247; nb=2,s=16 -> 183;
    // nb=1,s=16 -> 119; else direct.
    int nb, splits;
    if      (ws_size >= (size_t)247 * MB) { nb = 4; splits = 8;  }
    else if (ws_size >= (size_t)183 * MB) { nb = 2; splits = 16; }
    else if (ws_size >= (size_t)119 * MB) { nb = 1; splits = 16; }
    else                                  { nb = 1; splits = 1;  }
    unsigned short* pvpart = (unsigned short*)(wsb + (size_t)(55 + nb * 32) * MB);

    prep_kernel<<<2304, 256, 0, stream>>>(w2, w3, wq, wk, wv, wb1, wb2, bq, bk,
                                          w2b, w3b, wqb, wkb, wvb, wr1, wr2, bqk);
    stem1_kernel<<<4096, 256, 0, stream>>>(x, w1, b1, h1T);

    gemm_fullk<1, 64><<<dim3(1, 32, 4), 256, 0, stream>>>(
        h1T, 64, 4096L * 64, w2b, 64, 0,
        h2T, 128, 4096L * 128, b2, nullptr);
    gemm_fullk<1, 128><<<dim3(2, 32, 4), 256, 0, stream>>>(
        h2T, 128, 4096L * 128, w3b, 128, 0,
        x3T, 256, 4096L * 256, b3, nullptr);
    gemm_fullk<2, 256><<<dim3(4, 32, 4), 256, 0, stream>>>(
        x3T, 256, 4096L * 256, wqb, 256, 0,
        qkT, 512, 4096L * 512, bqk, nullptr);
    conv3_v2<1><<<dim3(8, 32), 256, 0, stream>>>(x3T, wr1, bb1, t1T);
    conv3_v2<0><<<dim3(8, 32), 256, 0, stream>>>(t1T, wr2, bb2, cv);

    for (int b0 = 0; b0 < 4; b0 += nb) {
        // S: EST = bf16(exp(Q.K^T)) + column partials
        int nwgS = 256 * nb;
        gemm256<0><<<nwgS, 512, 0, stream>>>(
            qkT + (size_t)b0 * 4096 * 512, 512, 4096L * 512,
            qkT + (size_t)b0 * 4096 * 512 + 256, 512, 4096L * 512,
            256, 1, nb, ST, 4096, SS,
            part, nullptr, nullptr, nullptr, nullptr, nwgS / 8);
        recip_kernel<<<nb * 16, 256, 0, stream>>>(part, rcp);
        // V' = (Wv x3 + bv) * rcp[n]
        gemm_fullk<3, 256><<<dim3(32, 2, nb), 256, 0, stream>>>(
            wvb, 256, 0,
            x3T + (size_t)b0 * 4096 * 256, 256, 4096L * 256,
            vB, 4096, 256L * 4096, bv, rcp);
        // PV: split-K, BK=32 2-blocks/CU pipeline
        int nwgP = 16 * splits * nb;
        gemm256<4><<<nwgP, 512, 0, stream>>>(
            vB, 4096, 256L * 4096, ST, 4096, SS,
            4096 / splits, splits, nb,
            out + (size_t)b0 * ONEM, 4096, ONEM,
            nullptr, pvpart, cv + (size_t)b0 * ONEM, alpha, beta, nwgP / 8);
        if (splits > 1)
            reduce_kernel<<<nb * 1024, 256, 0, stream>>>(
                pvpart, cv + (size_t)b0 * ONEM, alpha, beta,
                out + (size_t)b0 * ONEM, splits, (long)nb * ONEM);
    }
}

// Round 12
// 254.296 us; speedup vs baseline: 2.6335x; 2.6335x over previous
//
#include <hip/hip_runtime.h>
#include <math.h>

#define NPIX 4096
#define CC   256

typedef __attribute__((ext_vector_type(8))) short bf16x8;
typedef __attribute__((ext_vector_type(4))) float f32x4;

__device__ inline unsigned short f2bf(float f) {
    unsigned u = __builtin_bit_cast(unsigned, f);
    u += 0x7FFF + ((u >> 16) & 1);              // RTN-E
    return (unsigned short)(u >> 16);
}
__device__ inline float bf2f(unsigned short h) {
    unsigned u = (unsigned)h << 16;
    return __builtin_bit_cast(float, u);
}
__device__ inline void gl_lds16(const void* g, void* l) {
    __builtin_amdgcn_global_load_lds(
        (const __attribute__((address_space(1))) void*)g,
        (__attribute__((address_space(3))) void*)l, 16, 0, 0);
}

// ---------------------------------------------------------------------------
// Weight prep (unchanged, verified)
// ---------------------------------------------------------------------------
__global__ __launch_bounds__(256) void prep_kernel(
    const float* __restrict__ w2, const float* __restrict__ w3,
    const float* __restrict__ wq, const float* __restrict__ wk,
    const float* __restrict__ wv, const float* __restrict__ wb1,
    const float* __restrict__ wb2, const float* __restrict__ bq,
    const float* __restrict__ bk,
    unsigned short* w2b, unsigned short* w3b, unsigned short* wqb,
    unsigned short* wkb, unsigned short* wvb,
    unsigned short* wr1, unsigned short* wr2, float* bqk) {
    int i = blockIdx.x * 256 + threadIdx.x;
    if (i < 8192)  w2b[i] = f2bf(w2[i]);
    if (i < 32768) w3b[i] = f2bf(w3[i]);
    if (i < 65536) { wqb[i] = f2bf(wq[i]); wkb[i] = f2bf(wk[i]); wvb[i] = f2bf(wv[i]); }
    if (i < 256)   { bqk[i] = bq[i]; bqk[256 + i] = bk[i]; }
    if (i < 589824) {
        int o = i / 2304; int r = i - o * 2304; int tap = r >> 8; int c = r & 255;
        wr1[i] = f2bf(wb1[(o * 256 + c) * 9 + tap]);
        wr2[i] = f2bf(wb2[(o * 256 + c) * 9 + tap]);
    }
}

// ---------------------------------------------------------------------------
// Stem (unchanged, verified)
// ---------------------------------------------------------------------------
__global__ __launch_bounds__(256) void stem1_kernel(
    const float* __restrict__ x, const float* __restrict__ w1,
    const float* __restrict__ b1, unsigned short* __restrict__ h1T) {
    int idx = blockIdx.x * 256 + threadIdx.x;
    int o = idx & 63;
    int p = (idx >> 6) & 4095;
    int b = idx >> 18;
    const float* xb = x + (size_t)b * 3 * NPIX + p;
    float acc = b1[o];
    acc = fmaf(w1[o * 3 + 0], xb[0],        acc);
    acc = fmaf(w1[o * 3 + 1], xb[NPIX],     acc);
    acc = fmaf(w1[o * 3 + 2], xb[2 * NPIX], acc);
    h1T[idx] = f2bf(fmaxf(acc, 0.f));
}

// ---------------------------------------------------------------------------
// Full-K single-stage GEMM (K<=256) — verified. conv2/conv3 1x1, q|k, V'.
// ---------------------------------------------------------------------------
template<int EPI, int KK>
__global__ __launch_bounds__(256) void gemm_fullk(
    const unsigned short* __restrict__ A, long lda, long sA,
    const unsigned short* __restrict__ BT, long ldb, long sB,
    void* __restrict__ Cp, long ldc, long sC,
    const float* __restrict__ bias, float* __restrict__ aux) {
    constexpr int SPR = KK / 8;
    constexpr int RPI = 64 / SPR;
    __shared__ unsigned short As[128 * KK];
    __shared__ unsigned short Bs[128 * KK];
    const int tid  = threadIdx.x;
    const int lane = tid & 63;
    const int wave = tid >> 6;
    const int wr = (wave >> 1) * 64, wc = (wave & 1) * 64;
    const int l15 = lane & 15, lh = lane >> 4;
    const int sl  = lane & (SPR - 1);
    const int rof = lane / SPR;
    const int z = blockIdx.z;
    const unsigned short* Ab = A  + (size_t)z * sA + (size_t)blockIdx.y * 128 * lda;
    const unsigned short* Bb = BT + (size_t)z * sB + (size_t)blockIdx.x * 128 * ldb;

    f32x4 acc[4][4];
    #pragma unroll
    for (int i = 0; i < 4; ++i)
        #pragma unroll
        for (int j = 0; j < 4; ++j) { f32x4 zr = {0.f, 0.f, 0.f, 0.f}; acc[i][j] = zr; }

    #pragma unroll
    for (int i = 0; i < KK / 16; ++i) {
        int r0  = wave * 32 + i * RPI;
        int row = r0 + rof;
        int cs  = (sl ^ (row & (SPR - 1))) * 8;
        gl_lds16(Ab + (size_t)row * lda + cs, &As[r0 * KK]);
        gl_lds16(Bb + (size_t)row * ldb + cs, &Bs[r0 * KK]);
    }
    __syncthreads();

    #pragma unroll
    for (int ks = 0; ks < KK / 32; ++ks) {
        bf16x8 a[4], b[4];
        #pragma unroll
        for (int f = 0; f < 4; ++f) {
            int ra = wr + f * 16 + l15;
            a[f] = *(const bf16x8*)&As[ra * KK + ((((ks << 2) + lh) ^ (ra & (SPR - 1))) << 3)];
            int rb = wc + f * 16 + l15;
            b[f] = *(const bf16x8*)&Bs[rb * KK + ((((ks << 2) + lh) ^ (rb & (SPR - 1))) << 3)];
        }
        #pragma unroll
        for (int i = 0; i < 4; ++i)
            #pragma unroll
            for (int j = 0; j < 4; ++j)
                acc[i][j] = __builtin_amdgcn_mfma_f32_16x16x32_bf16(
                    a[i], b[j], acc[i][j], 0, 0, 0);
    }

    const int row0 = blockIdx.y * 128 + wr;
    const int col0 = blockIdx.x * 128 + wc;
    unsigned short* OUT = (unsigned short*)Cp + (size_t)z * sC;
    #pragma unroll
    for (int i = 0; i < 4; ++i)
        #pragma unroll
        for (int j = 0; j < 4; ++j) {
            int cgl = col0 + j * 16 + l15;
            float bc = (EPI == 1 || EPI == 2) ? bias[cgl] : 0.f;
            float sc = (EPI == 3) ? aux[(size_t)z * 4096 + cgl] : 1.f;
            #pragma unroll
            for (int q = 0; q < 4; ++q) {
                int r = row0 + i * 16 + lh * 4 + q;
                float v = acc[i][j][q];
                if (EPI == 3) v = (v + bias[r]) * sc;
                else v += bc;
                if (EPI == 1) v = fmaxf(v, 0.f);
                OUT[(size_t)r * ldc + cgl] = f2bf(v);
            }
        }
}

// ---------------------------------------------------------------------------
// 256x256-tile GEMM, 8 waves, BK=64, m201-style counted-wait pipeline.
// Per tile (4 phases): P1{read aL,b01; stage A-h0(t+1)->NXTA}
//   P2{read b23; stage A-h1(t+1)->NXTA} P3{read aH; stage B-h0(t+2)->CURB}
//   P4{stage B-h1(t+2)->CURB; MFMA; vmcnt(4); bar}
// Each phase: bar; lgkm0; sched_barrier; prio1; 16 MFMA; prio0; bar.
// Ledger: A(t+1) overwrites A(t-1) (reads ended (t-1).P3, 2 barriers back);
// B(t+2) overwrites B(t) (reads ended t.P2). vmcnt(4) at t.P4 guarantees all
// loads issued <= t.P2 (i.e., A(t+1),B(t+1) complete) and leaves B(t+2)'s 4
// in flight — loads get 4-7 phases of air (never drain-0 in steady state).
// Tail: when stages guarded off, P4 uses vmcnt(0).
// EPI 0: S — store bf16(exp(acc)) + column-sum partials -> aux
// EPI 4: PV — split-K; splits==1: alpha*CV+beta*acc; else bf16 partials
// ---------------------------------------------------------------------------
#define PH_ENTER                                            \
    asm volatile("" ::: "memory");                          \
    __builtin_amdgcn_s_barrier();                           \
    asm volatile("s_waitcnt lgkmcnt(0)" ::: "memory");      \
    __builtin_amdgcn_sched_barrier(0);                      \
    __builtin_amdgcn_s_setprio(1);
#define PH_EXIT                                             \
    __builtin_amdgcn_s_setprio(0);                          \
    asm volatile("" ::: "memory");                          \
    __builtin_amdgcn_s_barrier();

#define DO_TILE(CURA, CURB, NXTA, KT)                                          \
{                                                                              \
    const int kn1 = (KT) + 1, kn2 = (KT) + 2;                                  \
    bf16x8 aL[4][2], aH[4][2], b01[2][2], b23[2][2];                           \
    /* P1: read aL + b01; stage A-h0(t+1) */                                   \
    _Pragma("unroll") for (int f = 0; f < 4; ++f) {                            \
        const unsigned short* rp = &(CURA)[(wr + f * 16 + l15) * 64];          \
        aL[f][0] = *(const bf16x8*)&rp[sa0];                                   \
        aL[f][1] = *(const bf16x8*)&rp[sa1];                                   \
    }                                                                          \
    _Pragma("unroll") for (int f = 0; f < 2; ++f) {                            \
        const unsigned short* rp = &(CURB)[(wc + f * 16 + l15) * 64];          \
        b01[f][0] = *(const bf16x8*)&rp[sa0];                                  \
        b01[f][1] = *(const bf16x8*)&rp[sa1];                                  \
    }                                                                          \
    if (kn1 < T) STAGE_A(NXTA, kn1 << 6, 0);                                   \
    PH_ENTER;                                                                  \
    _Pragma("unroll") for (int i = 0; i < 4; ++i)                              \
        _Pragma("unroll") for (int j = 0; j < 2; ++j)                          \
            _Pragma("unroll") for (int ks = 0; ks < 2; ++ks)                   \
                acc[i][j] = __builtin_amdgcn_mfma_f32_16x16x32_bf16(           \
                    aL[i][ks], b01[j][ks], acc[i][j], 0, 0, 0);                \
    PH_EXIT;                                                                   \
    /* P2: read b23; stage A-h1(t+1) */                                        \
    _Pragma("unroll") for (int f = 0; f < 2; ++f) {                            \
        const unsigned short* rp = &(CURB)[(wc + 32 + f * 16 + l15) * 64];     \
        b23[f][0] = *(const bf16x8*)&rp[sa0];                                  \
        b23[f][1] = *(const bf16x8*)&rp[sa1];                                  \
    }                                                                          \
    if (kn1 < T) STAGE_A(NXTA, kn1 << 6, 1);                                   \
    PH_ENTER;                                                                  \
    _Pragma("unroll") for (int i = 0; i < 4; ++i)                              \
        _Pragma("unroll") for (int j = 0; j < 2; ++j)                          \
            _Pragma("unroll") for (int ks = 0; ks < 2; ++ks)                   \
                acc[i][j + 2] = __builtin_amdgcn_mfma_f32_16x16x32_bf16(       \
                    aL[i][ks], b23[j][ks], acc[i][j + 2], 0, 0, 0);            \
    PH_EXIT;                                                                   \
    /* P3: read aH; stage B-h0(t+2) into CURB (B(t) reads done at P2) */       \
    _Pragma("unroll") for (int f = 0; f < 4; ++f) {                            \
        const unsigned short* rp = &(CURA)[(wr + 64 + f * 16 + l15) * 64];     \
        aH[f][0] = *(const bf16x8*)&rp[sa0];                                   \
        aH[f][1] = *(const bf16x8*)&rp[sa1];                                   \
    }                                                                          \
    if (kn2 < T) STAGE_B(CURB, kn2 << 6, 0);                                   \
    PH_ENTER;                                                                  \
    _Pragma("unroll") for (int i = 0; i < 4; ++i)                              \
        _Pragma("unroll") for (int j = 0; j < 2; ++j)                          \
            _Pragma("unroll") for (int ks = 0; ks < 2; ++ks)                   \
                acc[i + 4][j + 2] = __builtin_amdgcn_mfma_f32_16x16x32_bf16(   \
                    aH[i][ks], b23[j][ks], acc[i + 4][j + 2], 0, 0, 0);        \
    PH_EXIT;                                                                   \
    /* P4: stage B-h1(t+2); MFMA Q10; counted wait; trailing barrier */        \
    if (kn2 < T) STAGE_B(CURB, kn2 << 6, 1);                                   \
    PH_ENTER;                                                                  \
    _Pragma("unroll") for (int i = 0; i < 4; ++i)                              \
        _Pragma("unroll") for (int j = 0; j < 2; ++j)                          \
            _Pragma("unroll") for (int ks = 0; ks < 2; ++ks)                   \
                acc[i + 4][j] = __builtin_amdgcn_mfma_f32_16x16x32_bf16(       \
                    aH[i][ks], b01[j][ks], acc[i + 4][j], 0, 0, 0);            \
    __builtin_amdgcn_s_setprio(0);                                             \
    if (kn2 < T) { asm volatile("s_waitcnt vmcnt(4)" ::: "memory"); }          \
    else         { asm volatile("s_waitcnt vmcnt(0)" ::: "memory"); }          \
    asm volatile("" ::: "memory");                                             \
    __builtin_amdgcn_s_barrier();                                              \
}

template<int EPI>
__global__ __launch_bounds__(512) void gemm256(
    const unsigned short* __restrict__ A, long lda, long sA,
    const unsigned short* __restrict__ BT, long ldb, long sB,
    int Kc, int splits, int nb,
    void* __restrict__ Cp, long ldc, long sC,
    float* __restrict__ aux, unsigned short* __restrict__ partial,
    const unsigned short* __restrict__ CV,
    const float* __restrict__ alphaP, const float* __restrict__ betaP,
    int nwgc) {
    __shared__ unsigned short As0[256 * 64], As1[256 * 64];
    __shared__ unsigned short Bs0[256 * 64], Bs1[256 * 64];
    const int orig = blockIdx.x;
    const int wgid = (orig & 7) * nwgc + (orig >> 3);    // XCD-chunked, bijective
    int bx, by, sp, z;
    if (EPI == 0) { bx = wgid & 15; by = (wgid >> 4) & 15; z = wgid >> 8; sp = 0; }
    else          { bx = wgid & 15; sp = (wgid >> 4) % splits; z = wgid / (16 * splits); by = 0; }

    const int tid  = threadIdx.x;
    const int lane = tid & 63;
    const int wave = tid >> 6;
    const int wr = (wave >> 2) * 128;       // row half
    const int wc = (wave & 3) * 64;         // col quarter
    const int l15 = lane & 15, lh = lane >> 4;
    const int sl  = lane & 7, rof = lane >> 3;
    const int sa0 = ((lh ^ (l15 & 7)) << 3);             // frag-read swizzle ks=0
    const int sa1 = (((4 + lh) ^ (l15 & 7)) << 3);       // ks=1
    const unsigned short* Ab = A  + (size_t)z * sA + (size_t)by * 256 * lda + (size_t)sp * Kc;
    const unsigned short* Bb = BT + (size_t)z * sB + (size_t)bx * 256 * ldb + (size_t)sp * Kc;

    f32x4 acc[8][4];
    #pragma unroll
    for (int i = 0; i < 8; ++i)
        #pragma unroll
        for (int j = 0; j < 4; ++j) { f32x4 zr = {0.f, 0.f, 0.f, 0.f}; acc[i][j] = zr; }

    // stage one half (128 rows x 64 cols = 2 block-wide gl_lds)
    auto STAGE_A = [&](unsigned short* dst, int k0, int h) {
        #pragma unroll
        for (int s = 0; s < 2; ++s) {
            int rb  = h * 128 + s * 64 + wave * 8;
            int row = rb + rof;
            int cs  = (sl ^ (row & 7)) * 8;
            gl_lds16(Ab + (size_t)row * lda + k0 + cs, &dst[rb * 64]);
        }
    };
    auto STAGE_B = [&](unsigned short* dst, int k0, int h) {
        #pragma unroll
        for (int s = 0; s < 2; ++s) {
            int rb  = h * 128 + s * 64 + wave * 8;
            int row = rb + rof;
            int cs  = (sl ^ (row & 7)) * 8;
            gl_lds16(Bb + (size_t)row * ldb + k0 + cs, &dst[rb * 64]);
        }
    };

    const int T = Kc >> 6;                  // >= 4, even, at all call sites
    // prologue: tile0 A+B into buf0; tile1 B into Bs1 (A(t1) comes at 0.P1/P2)
    STAGE_A(As0, 0, 0); STAGE_A(As0, 0, 1);
    STAGE_B(Bs0, 0, 0); STAGE_B(Bs0, 0, 1);
    STAGE_B(Bs1, 64, 0); STAGE_B(Bs1, 64, 1);
    asm volatile("s_waitcnt vmcnt(4)" ::: "memory");  // tile0 landed; t1-B in flight
    __builtin_amdgcn_s_barrier();

    for (int kt = 0; kt < T; kt += 2) {
        DO_TILE(As0, Bs0, As1, kt);
        DO_TILE(As1, Bs1, As0, kt + 1);
    }

    if (EPI == 0) {
        unsigned short* OUT = (unsigned short*)Cp + (size_t)z * sC;
        const int row0 = by * 256 + wr;
        const int col0 = bx * 256 + wc;
        float cs4[4] = {0.f, 0.f, 0.f, 0.f};
        #pragma unroll
        for (int i = 0; i < 8; ++i)
            #pragma unroll
            for (int j = 0; j < 4; ++j) {
                int cgl = col0 + j * 16 + l15;
                #pragma unroll
                for (int q = 0; q < 4; ++q) {
                    int r = row0 + i * 16 + lh * 4 + q;
                    unsigned short h = f2bf(__expf(acc[i][j][q]));
                    OUT[(size_t)r * ldc + cgl] = h;
                    cs4[j] += bf2f(h);          // sum the ROUNDED numerator
                }
            }
        #pragma unroll
        for (int off = 16; off <= 32; off <<= 1)
            #pragma unroll
            for (int j = 0; j < 4; ++j)
                cs4[j] += __shfl_xor(cs4[j], off);
        if (lh == 0) {
            float* part = aux + (((size_t)z * 16 + by) * 2 + (wave >> 2)) * 4096;
            #pragma unroll
            for (int j = 0; j < 4; ++j)
                part[col0 + j * 16 + l15] = cs4[j];
        }
    } else {
        const int col0 = bx * 256 + wc;
        if (splits == 1) {
            float* OUT = (float*)Cp + (size_t)z * sC;
            const unsigned short* CVb = CV + (size_t)z * sC;
            const float al = alphaP[0], be = betaP[0];
            #pragma unroll
            for (int i = 0; i < 8; ++i)
                #pragma unroll
                for (int j = 0; j < 4; ++j) {
                    int cgl = col0 + j * 16 + l15;
                    #pragma unroll
                    for (int q = 0; q < 4; ++q) {
                        int r = wr + i * 16 + lh * 4 + q;
                        size_t o = (size_t)r * ldc + cgl;
                        OUT[o] = al * bf2f(CVb[o]) + be * acc[i][j][q];
                    }
                }
        } else {
            unsigned short* P = partial + ((size_t)sp * nb + z) * ((size_t)256 * 4096);
            #pragma unroll
            for (int i = 0; i < 8; ++i)
                #pragma unroll
                for (int j = 0; j < 4; ++j) {
                    int cgl = col0 + j * 16 + l15;
                    #pragma unroll
                    for (int q = 0; q < 4; ++q) {
                        int r = wr + i * 16 + lh * 4 + q;
                        P[(size_t)r * 4096 + cgl] = f2bf(acc[i][j][q]);
                    }
                }
        }
    }
}

// ---------------------------------------------------------------------------
// reduce: out = alpha*cv + beta * sum_sp bf16partial[sp]
// ---------------------------------------------------------------------------
__global__ __launch_bounds__(256) void reduce_kernel(
    const unsigned short* __restrict__ partial, const unsigned short* __restrict__ cvb,
    const float* __restrict__ alphaP, const float* __restrict__ betaP,
    float* __restrict__ outp, int splits, long chunk) {
    long idx = ((long)blockIdx.x * 256 + threadIdx.x) * 4;
    if (idx >= chunk) return;
    float s0 = 0.f, s1 = 0.f, s2 = 0.f, s3 = 0.f;
    for (int sp = 0; sp < splits; ++sp) {
        ushort4 p = *(const ushort4*)&partial[(size_t)sp * chunk + idx];
        s0 += bf2f(p.x); s1 += bf2f(p.y); s2 += bf2f(p.z); s3 += bf2f(p.w);
    }
    ushort4 c4 = *(const ushort4*)&cvb[idx];
    const float al = alphaP[0], be = betaP[0];
    float4 r;
    r.x = al * bf2f(c4.x) + be * s0;
    r.y = al * bf2f(c4.y) + be * s1;
    r.z = al * bf2f(c4.z) + be * s2;
    r.w = al * bf2f(c4.w) + be * s3;
    *(float4*)&outp[idx] = r;
}

// ---------------------------------------------------------------------------
// rcp[z][n] = 1 / sum over 32 partials (16 row-blocks x 2 halves)
// ---------------------------------------------------------------------------
__global__ __launch_bounds__(256) void recip_kernel(
    const float* __restrict__ part, float* __restrict__ rcp) {
    int idx = blockIdx.x * 256 + threadIdx.x;
    int z = idx >> 12, n = idx & 4095;
    const float* pb = part + (size_t)z * 32 * 4096 + n;
    float s = 0.f;
    #pragma unroll 8
    for (int t = 0; t < 32; ++t) s += pb[(size_t)t * 4096];
    rcp[idx] = 1.f / s;
}

// ---------------------------------------------------------------------------
// 3x3 SAME conv v2 (unchanged, verified rounds 7-11)
// ---------------------------------------------------------------------------
template<int PIXOUT>
__global__ __launch_bounds__(256) void conv3_v2(
    const unsigned short* __restrict__ X, const unsigned short* __restrict__ Wr,
    const float* __restrict__ bias, void* __restrict__ Outp) {
    __shared__ unsigned short wt[9 * 128 * 40];
    __shared__ unsigned short patch[264 * 40];
    const int tid  = threadIdx.x;
    const int lane = tid & 63;
    const int wave = tid >> 6;
    const int l15 = lane & 15, lh = lane >> 4;
    const int oh = blockIdx.x & 1;
    const int b  = blockIdx.x >> 1;
    const int h0 = blockIdx.y;
    const int wy = (wave >> 1) * 64, wx = (wave & 1) * 64;
    const int obase = PIXOUT ? wx : wy;
    const int pbase = PIXOUT ? wy : wx;
    const unsigned short* Xb  = X + (size_t)b * (NPIX * CC);
    const unsigned short* Wro = Wr + (size_t)oh * 128 * 2304;

    f32x4 acc[4][4];
    #pragma unroll
    for (int i = 0; i < 4; ++i)
        #pragma unroll
        for (int j = 0; j < 4; ++j) { f32x4 zr = {0.f, 0.f, 0.f, 0.f}; acc[i][j] = zr; }

    for (int c0 = 0; c0 < 256; c0 += 32) {
        __syncthreads();
        #pragma unroll
        for (int t = 0; t < 5; ++t) {
            int q = t * 256 + tid;
            if (q < 1056) {
                int slot = q >> 2, cg = (q & 3) * 8;
                int r = slot / 66, w = slot - r * 66;
                int hh = h0 * 2 - 1 + r, ww = w - 1;
                int4 v = make_int4(0, 0, 0, 0);
                if ((unsigned)hh < 64u && (unsigned)ww < 64u)
                    v = *(const int4*)&Xb[(size_t)(hh * 64 + ww) * 256 + c0 + cg];
                *(int4*)&patch[slot * 40 + cg] = v;
            }
        }
        #pragma unroll
        for (int t = 0; t < 18; ++t) {
            int q = t * 256 + tid;
            int o = q / 36, rem = q - o * 36;
            int tap = rem >> 2, cg = (rem & 3) * 8;
            int4 v = *(const int4*)&Wro[(size_t)o * 2304 + tap * 256 + c0 + cg];
            *(int4*)&wt[(tap * 128 + o) * 40 + cg] = v;
        }
        __syncthreads();
        #pragma unroll
        for (int tap = 0; tap < 9; ++tap) {
            const int dy = tap / 3 - 1, dx = tap % 3 - 1;
            bf16x8 wf[4], pf[4];
            #pragma unroll
            for (int f = 0; f < 4; ++f) {
                int o = obase + f * 16 + l15;
                wf[f] = *(const bf16x8*)&wt[(tap * 128 + o) * 40 + lh * 8];
                int p = pbase + f * 16 + l15;
                int slot = ((p >> 6) + dy + 1) * 66 + (p & 63) + dx + 1;
                pf[f] = *(const bf16x8*)&patch[slot * 40 + lh * 8];
            }
            #pragma unroll
            for (int i = 0; i < 4; ++i)
                #pragma unroll
                for (int j = 0; j < 4; ++j) {
                    if (PIXOUT)
                        acc[i][j] = __builtin_amdgcn_mfma_f32_16x16x32_bf16(
                            pf[i], wf[j], acc[i][j], 0, 0, 0);
                    else
                        acc[i][j] = __builtin_amdgcn_mfma_f32_16x16x32_bf16(
                            wf[i], pf[j], acc[i][j], 0, 0, 0);
                }
        }
    }

    const int P0 = h0 * 128;
    if (PIXOUT) {
        unsigned short* O = (unsigned short*)Outp + (size_t)b * (NPIX * CC);
        #pragma unroll
        for (int i = 0; i < 4; ++i)
            #pragma unroll
            for (int j = 0; j < 4; ++j) {
                int o = oh * 128 + obase + j * 16 + l15;
                float bb = bias[o];
                #pragma unroll
                for (int q = 0; q < 4; ++q) {
                    int p = pbase + i * 16 + lh * 4 + q;
                    float v = fmaxf(acc[i][j][q] + bb, 0.f);
                    O[(size_t)(P0 + p) * CC + o] = f2bf(v);
                }
            }
    } else {
        unsigned short* O = (unsigned short*)Outp + (size_t)b * (CC * NPIX);
        #pragma unroll
        for (int i = 0; i < 4; ++i)
            #pragma unroll
            for (int j = 0; j < 4; ++j) {
                #pragma unroll
                for (int q = 0; q < 4; ++q) {
                    int o = oh * 128 + obase + i * 16 + lh * 4 + q;
                    int p = pbase + j * 16 + l15;
                    O[(size_t)o * NPIX + P0 + p] = f2bf(acc[i][j][q] + bias[o]);
                }
            }
    }
}

// ---------------------------------------------------------------------------
extern "C" void kernel_launch(void* const* d_in, const int* in_sizes, int n_in,
                              void* d_out, int out_size, void* d_ws, size_t ws_size,
                              hipStream_t stream) {
    const float* x   = (const float*)d_in[0];
    const float* w1  = (const float*)d_in[1];  const float* b1  = (const float*)d_in[2];
    const float* w2  = (const float*)d_in[3];  const float* b2  = (const float*)d_in[4];
    const float* w3  = (const float*)d_in[5];  const float* b3  = (const float*)d_in[6];
    const float* wb1 = (const float*)d_in[7];  const float* bb1 = (const float*)d_in[8];
    const float* wb2 = (const float*)d_in[9];  const float* bb2 = (const float*)d_in[10];
    const float* wq  = (const float*)d_in[11]; const float* bq  = (const float*)d_in[12];
    const float* wk  = (const float*)d_in[13]; const float* bk  = (const float*)d_in[14];
    const float* wv  = (const float*)d_in[15]; const float* bv  = (const float*)d_in[16];
    const float* alpha = (const float*)d_in[17];
    const float* beta  = (const float*)d_in[18];

    const size_t MB = 1 << 20;
    char* wsb = (char*)d_ws;
    unsigned short* x3T = (unsigned short*)(wsb + 0 * MB);   // [4][4096][256]
    unsigned short* qkT = (unsigned short*)(wsb + 8 * MB);   // [4][4096][512]
    unsigned short* cv  = (unsigned short*)(wsb + 24 * MB);  // [4][256][4096] bf16
    unsigned short* t1T = (unsigned short*)(wsb + 32 * MB);  // [4][4096][256]
    unsigned short* h1T = (unsigned short*)(wsb + 32 * MB);  // overlay
    unsigned short* h2T = (unsigned short*)(wsb + 34 * MB);  // overlay
    unsigned short* vB  = (unsigned short*)(wsb + 40 * MB);  // [nb][256][4096] bf16
    unsigned short* w2b = (unsigned short*)(wsb + 48 * MB);
    unsigned short* w3b = w2b + 8192;
    unsigned short* wqb = w3b + 32768;
    unsigned short* wkb = wqb + 65536;
    unsigned short* wvb = wkb + 65536;
    unsigned short* wr1 = wvb + 65536;
    unsigned short* wr2 = wr1 + 589824;
    float*          bqk  = (float*)(wsb + 51 * MB);
    float*          part = (float*)(wsb + 52 * MB);          // [nb][16][2][4096]
    float*          rcp  = (float*)(wsb + 54 * MB);          // [nb][4096]
    unsigned short* ST   = (unsigned short*)(wsb + 55 * MB); // [nb][4096][4096] bf16
    float* out = (float*)d_out;
    const long ONEM = (long)CC * NPIX;
    const long SS = 4096L * 4096;

    // gates: 55 + nb*32 (ST) + splits*nb*2 (bf16 partials) MB
    int nb, splits;
    if      (ws_size >= (size_t)247 * MB) { nb = 4; splits = 8;  }
    else if (ws_size >= (size_t)183 * MB) { nb = 2; splits = 16; }
    else if (ws_size >= (size_t)119 * MB) { nb = 1; splits = 16; }
    else                                  { nb = 1; splits = 1;  }
    unsigned short* pvpart = (unsigned short*)(wsb + (size_t)(55 + nb * 32) * MB);

    prep_kernel<<<2304, 256, 0, stream>>>(w2, w3, wq, wk, wv, wb1, wb2, bq, bk,
                                          w2b, w3b, wqb, wkb, wvb, wr1, wr2, bqk);
    stem1_kernel<<<4096, 256, 0, stream>>>(x, w1, b1, h1T);

    gemm_fullk<1, 64><<<dim3(1, 32, 4), 256, 0, stream>>>(
        h1T, 64, 4096L * 64, w2b, 64, 0,
        h2T, 128, 4096L * 128, b2, nullptr);
    gemm_fullk<1, 128><<<dim3(2, 32, 4), 256, 0, stream>>>(
        h2T, 128, 4096L * 128, w3b, 128, 0,
        x3T, 256, 4096L * 256, b3, nullptr);
    gemm_fullk<2, 256><<<dim3(4, 32, 4), 256, 0, stream>>>(
        x3T, 256, 4096L * 256, wqb, 256, 0,
        qkT, 512, 4096L * 512, bqk, nullptr);
    conv3_v2<1><<<dim3(8, 32), 256, 0, stream>>>(x3T, wr1, bb1, t1T);
    conv3_v2<0><<<dim3(8, 32), 256, 0, stream>>>(t1T, wr2, bb2, cv);

    for (int b0 = 0; b0 < 4; b0 += nb) {
        // S: EST = bf16(exp(Q.K^T)) + column partials
        int nwgS = 256 * nb;
        gemm256<0><<<nwgS, 512, 0, stream>>>(
            qkT + (size_t)b0 * 4096 * 512, 512, 4096L * 512,
            qkT + (size_t)b0 * 4096 * 512 + 256, 512, 4096L * 512,
            256, 1, nb, ST, 4096, SS,
            part, nullptr, nullptr, nullptr, nullptr, nwgS / 8);
        recip_kernel<<<nb * 16, 256, 0, stream>>>(part, rcp);
        // V' = (Wv x3 + bv) * rcp[n]
        gemm_fullk<3, 256><<<dim3(32, 2, nb), 256, 0, stream>>>(
            wvb, 256, 0,
            x3T + (size_t)b0 * 4096 * 256, 256, 4096L * 256,
            vB, 4096, 256L * 4096, bv, rcp);
        // PV: split-K, counted-wait pipeline
        int nwgP = 16 * splits * nb;
        gemm256<4><<<nwgP, 512, 0, stream>>>(
            vB, 4096, 256L * 4096, ST, 4096, SS,
            4096 / splits, splits, nb,
            out + (size_t)b0 * ONEM, 4096, ONEM,
            nullptr, pvpart, cv + (size_t)b0 * ONEM, alpha, beta, nwgP / 8);
        if (splits > 1)
            reduce_kernel<<<nb * 1024, 256, 0, stream>>>(
                pvpart, cv + (size_t)b0 * ONEM, alpha, beta,
                out + (size_t)b0 * ONEM, splits, (long)nb * ONEM);
    }
}

// Round 13
// 240.297 us; speedup vs baseline: 2.7869x; 1.0583x over previous
//
#include <hip/hip_runtime.h>
#include <math.h>

#define NPIX 4096
#define CC   256

typedef __attribute__((ext_vector_type(8))) short bf16x8;
typedef __attribute__((ext_vector_type(4))) float f32x4;

__device__ inline unsigned short f2bf(float f) {
    unsigned u = __builtin_bit_cast(unsigned, f);
    u += 0x7FFF + ((u >> 16) & 1);              // RTN-E
    return (unsigned short)(u >> 16);
}
__device__ inline float bf2f(unsigned short h) {
    unsigned u = (unsigned)h << 16;
    return __builtin_bit_cast(float, u);
}
__device__ inline void gl_lds16(const void* g, void* l) {
    __builtin_amdgcn_global_load_lds(
        (const __attribute__((address_space(1))) void*)g,
        (__attribute__((address_space(3))) void*)l, 16, 0, 0);
}

// ---------------------------------------------------------------------------
// Weight prep (unchanged, verified)
// ---------------------------------------------------------------------------
__global__ __launch_bounds__(256) void prep_kernel(
    const float* __restrict__ w2, const float* __restrict__ w3,
    const float* __restrict__ wq, const float* __restrict__ wk,
    const float* __restrict__ wv, const float* __restrict__ wb1,
    const float* __restrict__ wb2, const float* __restrict__ bq,
    const float* __restrict__ bk,
    unsigned short* w2b, unsigned short* w3b, unsigned short* wqb,
    unsigned short* wkb, unsigned short* wvb,
    unsigned short* wr1, unsigned short* wr2, float* bqk) {
    int i = blockIdx.x * 256 + threadIdx.x;
    if (i < 8192)  w2b[i] = f2bf(w2[i]);
    if (i < 32768) w3b[i] = f2bf(w3[i]);
    if (i < 65536) { wqb[i] = f2bf(wq[i]); wkb[i] = f2bf(wk[i]); wvb[i] = f2bf(wv[i]); }
    if (i < 256)   { bqk[i] = bq[i]; bqk[256 + i] = bk[i]; }
    if (i < 589824) {
        int o = i / 2304; int r = i - o * 2304; int tap = r >> 8; int c = r & 255;
        wr1[i] = f2bf(wb1[(o * 256 + c) * 9 + tap]);
        wr2[i] = f2bf(wb2[(o * 256 + c) * 9 + tap]);
    }
}

// ---------------------------------------------------------------------------
// Stem (unchanged, verified)
// ---------------------------------------------------------------------------
__global__ __launch_bounds__(256) void stem1_kernel(
    const float* __restrict__ x, const float* __restrict__ w1,
    const float* __restrict__ b1, unsigned short* __restrict__ h1T) {
    int idx = blockIdx.x * 256 + threadIdx.x;
    int o = idx & 63;
    int p = (idx >> 6) & 4095;
    int b = idx >> 18;
    const float* xb = x + (size_t)b * 3 * NPIX + p;
    float acc = b1[o];
    acc = fmaf(w1[o * 3 + 0], xb[0],        acc);
    acc = fmaf(w1[o * 3 + 1], xb[NPIX],     acc);
    acc = fmaf(w1[o * 3 + 2], xb[2 * NPIX], acc);
    h1T[idx] = f2bf(fmaxf(acc, 0.f));
}

// ---------------------------------------------------------------------------
// Full-K single-stage GEMM (K<=256) — verified. conv2/conv3 1x1, q|k, V'.
// ---------------------------------------------------------------------------
template<int EPI, int KK>
__global__ __launch_bounds__(256) void gemm_fullk(
    const unsigned short* __restrict__ A, long lda, long sA,
    const unsigned short* __restrict__ BT, long ldb, long sB,
    void* __restrict__ Cp, long ldc, long sC,
    const float* __restrict__ bias, float* __restrict__ aux) {
    constexpr int SPR = KK / 8;
    constexpr int RPI = 64 / SPR;
    __shared__ unsigned short As[128 * KK];
    __shared__ unsigned short Bs[128 * KK];
    const int tid  = threadIdx.x;
    const int lane = tid & 63;
    const int wave = tid >> 6;
    const int wr = (wave >> 1) * 64, wc = (wave & 1) * 64;
    const int l15 = lane & 15, lh = lane >> 4;
    const int sl  = lane & (SPR - 1);
    const int rof = lane / SPR;
    const int z = blockIdx.z;
    const unsigned short* Ab = A  + (size_t)z * sA + (size_t)blockIdx.y * 128 * lda;
    const unsigned short* Bb = BT + (size_t)z * sB + (size_t)blockIdx.x * 128 * ldb;

    f32x4 acc[4][4];
    #pragma unroll
    for (int i = 0; i < 4; ++i)
        #pragma unroll
        for (int j = 0; j < 4; ++j) { f32x4 zr = {0.f, 0.f, 0.f, 0.f}; acc[i][j] = zr; }

    #pragma unroll
    for (int i = 0; i < KK / 16; ++i) {
        int r0  = wave * 32 + i * RPI;
        int row = r0 + rof;
        int cs  = (sl ^ (row & (SPR - 1))) * 8;
        gl_lds16(Ab + (size_t)row * lda + cs, &As[r0 * KK]);
        gl_lds16(Bb + (size_t)row * ldb + cs, &Bs[r0 * KK]);
    }
    __syncthreads();

    #pragma unroll
    for (int ks = 0; ks < KK / 32; ++ks) {
        bf16x8 a[4], b[4];
        #pragma unroll
        for (int f = 0; f < 4; ++f) {
            int ra = wr + f * 16 + l15;
            a[f] = *(const bf16x8*)&As[ra * KK + ((((ks << 2) + lh) ^ (ra & (SPR - 1))) << 3)];
            int rb = wc + f * 16 + l15;
            b[f] = *(const bf16x8*)&Bs[rb * KK + ((((ks << 2) + lh) ^ (rb & (SPR - 1))) << 3)];
        }
        #pragma unroll
        for (int i = 0; i < 4; ++i)
            #pragma unroll
            for (int j = 0; j < 4; ++j)
                acc[i][j] = __builtin_amdgcn_mfma_f32_16x16x32_bf16(
                    a[i], b[j], acc[i][j], 0, 0, 0);
    }

    const int row0 = blockIdx.y * 128 + wr;
    const int col0 = blockIdx.x * 128 + wc;
    unsigned short* OUT = (unsigned short*)Cp + (size_t)z * sC;
    #pragma unroll
    for (int i = 0; i < 4; ++i)
        #pragma unroll
        for (int j = 0; j < 4; ++j) {
            int cgl = col0 + j * 16 + l15;
            float bc = (EPI == 1 || EPI == 2) ? bias[cgl] : 0.f;
            float sc = (EPI == 3) ? aux[(size_t)z * 4096 + cgl] : 1.f;
            #pragma unroll
            for (int q = 0; q < 4; ++q) {
                int r = row0 + i * 16 + lh * 4 + q;
                float v = acc[i][j][q];
                if (EPI == 3) v = (v + bias[r]) * sc;
                else v += bc;
                if (EPI == 1) v = fmaxf(v, 0.f);
                OUT[(size_t)r * ldc + cgl] = f2bf(v);
            }
        }
}

// ---------------------------------------------------------------------------
// 128x128-tile GEMM, 4 waves, BK=64 dbuf = 64 KB LDS -> 2 BLOCKS/CU (the R12
// lesson: 256^2/128KB was pinned at 1 block/CU and all schedules equal).
// R8-verified two-barrier counted-vmcnt loop: {STAGE(t+1); vmcnt(8); bar;
// prio1; MFMA(cur); prio0; bar}. XOR row&7 slot swizzle both sides.
// EPI 0: S — store bf16(exp(acc)) + column-sum partials -> aux
// EPI 4: PV — split-K; splits==1: alpha*CV+beta*acc; else bf16 partials
// ---------------------------------------------------------------------------
template<int EPI>
__global__ __launch_bounds__(256) void gemm128(
    const unsigned short* __restrict__ A, long lda, long sA,
    const unsigned short* __restrict__ BT, long ldb, long sB,
    int Kc, int splits, int nb,
    void* __restrict__ Cp, long ldc, long sC,
    float* __restrict__ aux, unsigned short* __restrict__ partial,
    const unsigned short* __restrict__ CV,
    const float* __restrict__ alphaP, const float* __restrict__ betaP,
    int nwgc) {
    __shared__ unsigned short As[2][128 * 64];
    __shared__ unsigned short Bs[2][128 * 64];
    const int orig = blockIdx.x;
    const int wgid = (orig & 7) * nwgc + (orig >> 3);    // XCD-chunked, bijective
    int bx, by, sp, z;
    if (EPI == 0) {
        bx = wgid & 31; by = (wgid >> 5) & 31; z = wgid >> 10; sp = 0;
    } else {
        bx = wgid & 31; by = (wgid >> 5) & 1;            // by = c-half
        sp = (wgid >> 6) % splits; z = wgid / (64 * splits);
    }

    const int tid  = threadIdx.x;
    const int lane = tid & 63;
    const int wave = tid >> 6;
    const int wr = (wave >> 1) * 64, wc = (wave & 1) * 64;
    const int l15 = lane & 15, lh = lane >> 4;
    const int sl  = lane & 7, rof = lane >> 3;
    const unsigned short* Ab = A  + (size_t)z * sA + (size_t)by * 128 * lda + (size_t)sp * Kc;
    const unsigned short* Bb = BT + (size_t)z * sB + (size_t)bx * 128 * ldb + (size_t)sp * Kc;

    f32x4 acc[4][4];
    #pragma unroll
    for (int i = 0; i < 4; ++i)
        #pragma unroll
        for (int j = 0; j < 4; ++j) { f32x4 zr = {0.f, 0.f, 0.f, 0.f}; acc[i][j] = zr; }

    auto STAGE = [&](int buf, int k0) {       // 8 gl_lds per wave (4 A + 4 B)
        #pragma unroll
        for (int s = 0; s < 4; ++s) {
            int rb  = wave * 8 + s * 32;
            int row = rb + rof;
            int cs  = (sl ^ (row & 7)) * 8;
            gl_lds16(Ab + (size_t)row * lda + k0 + cs, &As[buf][rb * 64]);
            gl_lds16(Bb + (size_t)row * ldb + k0 + cs, &Bs[buf][rb * 64]);
        }
    };

    STAGE(0, 0);
    const int T = Kc >> 6;
    for (int t = 0; t < T; ++t) {
        const int cur = t & 1;
        if (t + 1 < T) {
            STAGE(cur ^ 1, (t + 1) << 6);     // next tile stays in flight
            asm volatile("s_waitcnt vmcnt(8)" ::: "memory");   // tile t landed
        } else {
            asm volatile("s_waitcnt vmcnt(0)" ::: "memory");
        }
        __builtin_amdgcn_s_barrier();
        asm volatile("" ::: "memory");
        __builtin_amdgcn_s_setprio(1);
        #pragma unroll
        for (int ks = 0; ks < 2; ++ks) {
            bf16x8 a[4], b[4];
            #pragma unroll
            for (int f = 0; f < 4; ++f) {
                int ra = wr + f * 16 + l15;
                a[f] = *(const bf16x8*)&As[cur][ra * 64 + ((((ks << 2) + lh) ^ (ra & 7)) << 3)];
                int rb = wc + f * 16 + l15;
                b[f] = *(const bf16x8*)&Bs[cur][rb * 64 + ((((ks << 2) + lh) ^ (rb & 7)) << 3)];
            }
            #pragma unroll
            for (int i = 0; i < 4; ++i)
                #pragma unroll
                for (int j = 0; j < 4; ++j)
                    acc[i][j] = __builtin_amdgcn_mfma_f32_16x16x32_bf16(
                        a[i], b[j], acc[i][j], 0, 0, 0);
        }
        __builtin_amdgcn_s_setprio(0);
        asm volatile("" ::: "memory");
        __builtin_amdgcn_s_barrier();
    }

    if (EPI == 0) {
        unsigned short* OUT = (unsigned short*)Cp + (size_t)z * sC;
        const int row0 = by * 128 + wr;
        const int col0 = bx * 128 + wc;
        float cs4[4] = {0.f, 0.f, 0.f, 0.f};
        #pragma unroll
        for (int i = 0; i < 4; ++i)
            #pragma unroll
            for (int j = 0; j < 4; ++j) {
                int cgl = col0 + j * 16 + l15;
                #pragma unroll
                for (int q = 0; q < 4; ++q) {
                    int r = row0 + i * 16 + lh * 4 + q;
                    unsigned short h = f2bf(__expf(acc[i][j][q]));
                    OUT[(size_t)r * ldc + cgl] = h;
                    cs4[j] += bf2f(h);          // sum the ROUNDED numerator
                }
            }
        #pragma unroll
        for (int off = 16; off <= 32; off <<= 1)    // reduce over lh (rows)
            #pragma unroll
            for (int j = 0; j < 4; ++j)
                cs4[j] += __shfl_xor(cs4[j], off);
        if (lh == 0) {
            float* part = aux + (((size_t)z * 32 + by) * 2 + (wave >> 1)) * 4096;
            #pragma unroll
            for (int j = 0; j < 4; ++j)
                part[col0 + j * 16 + l15] = cs4[j];
        }
    } else {
        const int col0 = bx * 128 + wc;
        const int row0 = by * 128 + wr;
        if (splits == 1) {
            float* OUT = (float*)Cp + (size_t)z * sC;
            const unsigned short* CVb = CV + (size_t)z * sC;
            const float al = alphaP[0], be = betaP[0];
            #pragma unroll
            for (int i = 0; i < 4; ++i)
                #pragma unroll
                for (int j = 0; j < 4; ++j) {
                    int cgl = col0 + j * 16 + l15;
                    #pragma unroll
                    for (int q = 0; q < 4; ++q) {
                        int r = row0 + i * 16 + lh * 4 + q;
                        size_t o = (size_t)r * ldc + cgl;
                        OUT[o] = al * bf2f(CVb[o]) + be * acc[i][j][q];
                    }
                }
        } else {
            unsigned short* P = partial + ((size_t)sp * nb + z) * ((size_t)256 * 4096);
            #pragma unroll
            for (int i = 0; i < 4; ++i)
                #pragma unroll
                for (int j = 0; j < 4; ++j) {
                    int cgl = col0 + j * 16 + l15;
                    #pragma unroll
                    for (int q = 0; q < 4; ++q) {
                        int r = row0 + i * 16 + lh * 4 + q;
                        P[(size_t)r * 4096 + cgl] = f2bf(acc[i][j][q]);
                    }
                }
        }
    }
}

// ---------------------------------------------------------------------------
// reduce: out = alpha*cv + beta * sum_sp bf16partial[sp]
// ---------------------------------------------------------------------------
__global__ __launch_bounds__(256) void reduce_kernel(
    const unsigned short* __restrict__ partial, const unsigned short* __restrict__ cvb,
    const float* __restrict__ alphaP, const float* __restrict__ betaP,
    float* __restrict__ outp, int splits, long chunk) {
    long idx = ((long)blockIdx.x * 256 + threadIdx.x) * 4;
    if (idx >= chunk) return;
    float s0 = 0.f, s1 = 0.f, s2 = 0.f, s3 = 0.f;
    for (int sp = 0; sp < splits; ++sp) {
        ushort4 p = *(const ushort4*)&partial[(size_t)sp * chunk + idx];
        s0 += bf2f(p.x); s1 += bf2f(p.y); s2 += bf2f(p.z); s3 += bf2f(p.w);
    }
    ushort4 c4 = *(const ushort4*)&cvb[idx];
    const float al = alphaP[0], be = betaP[0];
    float4 r;
    r.x = al * bf2f(c4.x) + be * s0;
    r.y = al * bf2f(c4.y) + be * s1;
    r.z = al * bf2f(c4.z) + be * s2;
    r.w = al * bf2f(c4.w) + be * s3;
    *(float4*)&outp[idx] = r;
}

// ---------------------------------------------------------------------------
// rcp[z][n] = 1 / sum over 64 partials (32 row-blocks x 2 halves)
// ---------------------------------------------------------------------------
__global__ __launch_bounds__(256) void recip_kernel(
    const float* __restrict__ part, float* __restrict__ rcp) {
    int idx = blockIdx.x * 256 + threadIdx.x;
    int z = idx >> 12, n = idx & 4095;
    const float* pb = part + (size_t)z * 64 * 4096 + n;
    float s = 0.f;
    #pragma unroll 8
    for (int t = 0; t < 64; ++t) s += pb[(size_t)t * 4096];
    rcp[idx] = 1.f / s;
}

// ---------------------------------------------------------------------------
// 3x3 SAME conv v3: 64-o x 128-px blocks -> wt 46KB + patch 21KB = 67 KB LDS
// -> 2 blocks/CU (160 KB budget), grid (16,32) = 512 = 2/CU, 8 waves/CU.
// Wave tile: 32 o x 64 px. Same staging/frag patterns as verified v2.
// ---------------------------------------------------------------------------
template<int PIXOUT>
__global__ __launch_bounds__(256) void conv3_v3(
    const unsigned short* __restrict__ X, const unsigned short* __restrict__ Wr,
    const float* __restrict__ bias, void* __restrict__ Outp) {
    __shared__ unsigned short wt[9 * 64 * 40];   // [tap][o<64][32c pad40]
    __shared__ unsigned short patch[264 * 40];
    const int tid  = threadIdx.x;
    const int lane = tid & 63;
    const int wave = tid >> 6;
    const int l15 = lane & 15, lh = lane >> 4;
    const int ob = blockIdx.x & 3;              // 64-o block (0..3)
    const int b  = blockIdx.x >> 2;
    const int h0 = blockIdx.y;
    const int obase = (wave & 1) * 32;
    const int pbase = (wave >> 1) * 64;
    const unsigned short* Xb  = X + (size_t)b * (NPIX * CC);
    const unsigned short* Wro = Wr + (size_t)ob * 64 * 2304;

    constexpr int NI = PIXOUT ? 4 : 2;
    constexpr int NJ = PIXOUT ? 2 : 4;
    f32x4 acc[NI][NJ];
    #pragma unroll
    for (int i = 0; i < NI; ++i)
        #pragma unroll
        for (int j = 0; j < NJ; ++j) { f32x4 zr = {0.f, 0.f, 0.f, 0.f}; acc[i][j] = zr; }

    for (int c0 = 0; c0 < 256; c0 += 32) {
        __syncthreads();                        // previous chunk's reads done
        // stage patch: 264 slots x 32 c (zero halo): 1056 int4
        #pragma unroll
        for (int t = 0; t < 5; ++t) {
            int q = t * 256 + tid;
            if (q < 1056) {
                int slot = q >> 2, cg = (q & 3) * 8;
                int r = slot / 66, w = slot - r * 66;
                int hh = h0 * 2 - 1 + r, ww = w - 1;
                int4 v = make_int4(0, 0, 0, 0);
                if ((unsigned)hh < 64u && (unsigned)ww < 64u)
                    v = *(const int4*)&Xb[(size_t)(hh * 64 + ww) * 256 + c0 + cg];
                *(int4*)&patch[slot * 40 + cg] = v;
            }
        }
        // stage weights: 9 taps x 64 o x 32 c = 2304 int4 (exact, t<9)
        #pragma unroll
        for (int t = 0; t < 9; ++t) {
            int q = t * 256 + tid;
            int o = q / 36, rem = q - o * 36;
            int tap = rem >> 2, cg = (rem & 3) * 8;
            int4 v = *(const int4*)&Wro[(size_t)o * 2304 + tap * 256 + c0 + cg];
            *(int4*)&wt[(tap * 64 + o) * 40 + cg] = v;
        }
        __syncthreads();
        #pragma unroll
        for (int tap = 0; tap < 9; ++tap) {
            const int dy = tap / 3 - 1, dx = tap % 3 - 1;
            bf16x8 wf[2], pf[4];
            #pragma unroll
            for (int f = 0; f < 2; ++f) {
                int o = obase + f * 16 + l15;
                wf[f] = *(const bf16x8*)&wt[(tap * 64 + o) * 40 + lh * 8];
            }
            #pragma unroll
            for (int f = 0; f < 4; ++f) {
                int p = pbase + f * 16 + l15;
                int slot = ((p >> 6) + dy + 1) * 66 + (p & 63) + dx + 1;
                pf[f] = *(const bf16x8*)&patch[slot * 40 + lh * 8];
            }
            if (PIXOUT) {
                #pragma unroll
                for (int i = 0; i < NI; ++i)
                    #pragma unroll
                    for (int j = 0; j < NJ; ++j)
                        acc[i][j] = __builtin_amdgcn_mfma_f32_16x16x32_bf16(
                            pf[i], wf[j], acc[i][j], 0, 0, 0);
            } else {
                #pragma unroll
                for (int i = 0; i < NI; ++i)
                    #pragma unroll
                    for (int j = 0; j < NJ; ++j)
                        acc[i][j] = __builtin_amdgcn_mfma_f32_16x16x32_bf16(
                            wf[i], pf[j], acc[i][j], 0, 0, 0);
            }
        }
    }

    const int P0 = h0 * 128;
    if (PIXOUT) {
        // acc[i=p-frag(4)][j=o-frag(2)]: row=p, col=o
        unsigned short* O = (unsigned short*)Outp + (size_t)b * (NPIX * CC);
        #pragma unroll
        for (int i = 0; i < 4; ++i)
            #pragma unroll
            for (int j = 0; j < 2; ++j) {
                int o = ob * 64 + obase + j * 16 + l15;
                float bb = bias[o];
                #pragma unroll
                for (int q = 0; q < 4; ++q) {
                    int p = pbase + i * 16 + lh * 4 + q;
                    float v = fmaxf(acc[i][j][q] + bb, 0.f);
                    O[(size_t)(P0 + p) * CC + o] = f2bf(v);
                }
            }
    } else {
        // acc[i=o-frag(2)][j=p-frag(4)]: row=o, col=p
        unsigned short* O = (unsigned short*)Outp + (size_t)b * (CC * NPIX);
        #pragma unroll
        for (int i = 0; i < 2; ++i)
            #pragma unroll
            for (int j = 0; j < 4; ++j) {
                #pragma unroll
                for (int q = 0; q < 4; ++q) {
                    int o = ob * 64 + obase + i * 16 + lh * 4 + q;
                    int p = pbase + j * 16 + l15;
                    O[(size_t)o * NPIX + P0 + p] = f2bf(acc[i][j][q] + bias[o]);
                }
            }
    }
}

// ---------------------------------------------------------------------------
extern "C" void kernel_launch(void* const* d_in, const int* in_sizes, int n_in,
                              void* d_out, int out_size, void* d_ws, size_t ws_size,
                              hipStream_t stream) {
    const float* x   = (const float*)d_in[0];
    const float* w1  = (const float*)d_in[1];  const float* b1  = (const float*)d_in[2];
    const float* w2  = (const float*)d_in[3];  const float* b2  = (const float*)d_in[4];
    const float* w3  = (const float*)d_in[5];  const float* b3  = (const float*)d_in[6];
    const float* wb1 = (const float*)d_in[7];  const float* bb1 = (const float*)d_in[8];
    const float* wb2 = (const float*)d_in[9];  const float* bb2 = (const float*)d_in[10];
    const float* wq  = (const float*)d_in[11]; const float* bq  = (const float*)d_in[12];
    const float* wk  = (const float*)d_in[13]; const float* bk  = (const float*)d_in[14];
    const float* wv  = (const float*)d_in[15]; const float* bv  = (const float*)d_in[16];
    const float* alpha = (const float*)d_in[17];
    const float* beta  = (const float*)d_in[18];

    const size_t MB = 1 << 20;
    char* wsb = (char*)d_ws;
    unsigned short* x3T = (unsigned short*)(wsb + 0 * MB);   // [4][4096][256]
    unsigned short* qkT = (unsigned short*)(wsb + 8 * MB);   // [4][4096][512]
    unsigned short* cv  = (unsigned short*)(wsb + 24 * MB);  // [4][256][4096] bf16
    unsigned short* t1T = (unsigned short*)(wsb + 32 * MB);  // [4][4096][256]
    unsigned short* h1T = (unsigned short*)(wsb + 32 * MB);  // overlay
    unsigned short* h2T = (unsigned short*)(wsb + 34 * MB);  // overlay
    unsigned short* vB  = (unsigned short*)(wsb + 40 * MB);  // [nb][256][4096] bf16
    unsigned short* w2b = (unsigned short*)(wsb + 48 * MB);
    unsigned short* w3b = w2b + 8192;
    unsigned short* wqb = w3b + 32768;
    unsigned short* wkb = wqb + 65536;
    unsigned short* wvb = wkb + 65536;
    unsigned short* wr1 = wvb + 65536;
    unsigned short* wr2 = wr1 + 589824;
    float*          bqk  = (float*)(wsb + 51 * MB);
    float*          part = (float*)(wsb + 52 * MB);          // [4][32][2][4096] f32
    float*          rcp  = (float*)(wsb + 56 * MB);          // [4][4096]
    unsigned short* ST   = (unsigned short*)(wsb + 57 * MB); // [nb][4096][4096] bf16
    float* out = (float*)d_out;
    const long ONEM = (long)CC * NPIX;
    const long SS = 4096L * 4096;

    // gates: 57 + nb*32 (ST) + splits*nb*2 (bf16 partials) MB
    int nb, splits;
    if      (ws_size >= (size_t)249 * MB) { nb = 4; splits = 8;  }
    else if (ws_size >= (size_t)185 * MB) { nb = 2; splits = 16; }
    else if (ws_size >= (size_t)121 * MB) { nb = 1; splits = 16; }
    else                                  { nb = 1; splits = 1;  }
    unsigned short* pvpart = (unsigned short*)(wsb + (size_t)(57 + nb * 32) * MB);

    prep_kernel<<<2304, 256, 0, stream>>>(w2, w3, wq, wk, wv, wb1, wb2, bq, bk,
                                          w2b, w3b, wqb, wkb, wvb, wr1, wr2, bqk);
    stem1_kernel<<<4096, 256, 0, stream>>>(x, w1, b1, h1T);

    gemm_fullk<1, 64><<<dim3(1, 32, 4), 256, 0, stream>>>(
        h1T, 64, 4096L * 64, w2b, 64, 0,
        h2T, 128, 4096L * 128, b2, nullptr);
    gemm_fullk<1, 128><<<dim3(2, 32, 4), 256, 0, stream>>>(
        h2T, 128, 4096L * 128, w3b, 128, 0,
        x3T, 256, 4096L * 256, b3, nullptr);
    gemm_fullk<2, 256><<<dim3(4, 32, 4), 256, 0, stream>>>(
        x3T, 256, 4096L * 256, wqb, 256, 0,
        qkT, 512, 4096L * 512, bqk, nullptr);
    conv3_v3<1><<<dim3(16, 32), 256, 0, stream>>>(x3T, wr1, bb1, t1T);
    conv3_v3<0><<<dim3(16, 32), 256, 0, stream>>>(t1T, wr2, bb2, cv);

    for (int b0 = 0; b0 < 4; b0 += nb) {
        // S: EST = bf16(exp(Q.K^T)) + column partials — 128^2, 2 blocks/CU
        int nwgS = 1024 * nb;
        gemm128<0><<<nwgS, 256, 0, stream>>>(
            qkT + (size_t)b0 * 4096 * 512, 512, 4096L * 512,
            qkT + (size_t)b0 * 4096 * 512 + 256, 512, 4096L * 512,
            256, 1, nb, ST, 4096, SS,
            part, nullptr, nullptr, nullptr, nullptr, nwgS / 8);
        recip_kernel<<<nb * 16, 256, 0, stream>>>(part, rcp);
        // V' = (Wv x3 + bv) * rcp[n]
        gemm_fullk<3, 256><<<dim3(32, 2, nb), 256, 0, stream>>>(
            wvb, 256, 0,
            x3T + (size_t)b0 * 4096 * 256, 256, 4096L * 256,
            vB, 4096, 256L * 4096, bv, rcp);
        // PV: split-K, 128^2, 2 blocks/CU
        int nwgP = 64 * splits * nb;
        gemm128<4><<<nwgP, 256, 0, stream>>>(
            vB, 4096, 256L * 4096, ST, 4096, SS,
            4096 / splits, splits, nb,
            out + (size_t)b0 * ONEM, 4096, ONEM,
            nullptr, pvpart, cv + (size_t)b0 * ONEM, alpha, beta, nwgP / 8);
        if (splits > 1)
            reduce_kernel<<<nb * 1024, 256, 0, stream>>>(
                pvpart, cv + (size_t)b0 * ONEM, alpha, beta,
                out + (size_t)b0 * ONEM, splits, (long)nb * ONEM);
    }
}

// Round 14
// 239.026 us; speedup vs baseline: 2.8017x; 1.0053x over previous
//
#include <hip/hip_runtime.h>
#include <math.h>

#define NPIX 4096
#define CC   256

typedef __attribute__((ext_vector_type(8))) short bf16x8;
typedef __attribute__((ext_vector_type(4))) float f32x4;

__device__ inline unsigned short f2bf(float f) {
    unsigned u = __builtin_bit_cast(unsigned, f);
    u += 0x7FFF + ((u >> 16) & 1);              // RTN-E
    return (unsigned short)(u >> 16);
}
__device__ inline float bf2f(unsigned short h) {
    unsigned u = (unsigned)h << 16;
    return __builtin_bit_cast(float, u);
}
__device__ inline void gl_lds16(const void* g, void* l) {
    __builtin_amdgcn_global_load_lds(
        (const __attribute__((address_space(1))) void*)g,
        (__attribute__((address_space(3))) void*)l, 16, 0, 0);
}

// ---------------------------------------------------------------------------
// Weight prep (unchanged, verified)
// ---------------------------------------------------------------------------
__global__ __launch_bounds__(256) void prep_kernel(
    const float* __restrict__ w2, const float* __restrict__ w3,
    const float* __restrict__ wq, const float* __restrict__ wk,
    const float* __restrict__ wv, const float* __restrict__ wb1,
    const float* __restrict__ wb2, const float* __restrict__ bq,
    const float* __restrict__ bk,
    unsigned short* w2b, unsigned short* w3b, unsigned short* wqb,
    unsigned short* wkb, unsigned short* wvb,
    unsigned short* wr1, unsigned short* wr2, float* bqk) {
    int i = blockIdx.x * 256 + threadIdx.x;
    if (i < 8192)  w2b[i] = f2bf(w2[i]);
    if (i < 32768) w3b[i] = f2bf(w3[i]);
    if (i < 65536) { wqb[i] = f2bf(wq[i]); wkb[i] = f2bf(wk[i]); wvb[i] = f2bf(wv[i]); }
    if (i < 256)   { bqk[i] = bq[i]; bqk[256 + i] = bk[i]; }
    if (i < 589824) {
        int o = i / 2304; int r = i - o * 2304; int tap = r >> 8; int c = r & 255;
        wr1[i] = f2bf(wb1[(o * 256 + c) * 9 + tap]);
        wr2[i] = f2bf(wb2[(o * 256 + c) * 9 + tap]);
    }
}

// ---------------------------------------------------------------------------
// Stem (unchanged, verified)
// ---------------------------------------------------------------------------
__global__ __launch_bounds__(256) void stem1_kernel(
    const float* __restrict__ x, const float* __restrict__ w1,
    const float* __restrict__ b1, unsigned short* __restrict__ h1T) {
    int idx = blockIdx.x * 256 + threadIdx.x;
    int o = idx & 63;
    int p = (idx >> 6) & 4095;
    int b = idx >> 18;
    const float* xb = x + (size_t)b * 3 * NPIX + p;
    float acc = b1[o];
    acc = fmaf(w1[o * 3 + 0], xb[0],        acc);
    acc = fmaf(w1[o * 3 + 1], xb[NPIX],     acc);
    acc = fmaf(w1[o * 3 + 2], xb[2 * NPIX], acc);
    h1T[idx] = f2bf(fmaxf(acc, 0.f));
}

// ---------------------------------------------------------------------------
// Full-K single-stage GEMM (K<=256) — verified. conv2/conv3 1x1, q|k, V'.
// ---------------------------------------------------------------------------
template<int EPI, int KK>
__global__ __launch_bounds__(256) void gemm_fullk(
    const unsigned short* __restrict__ A, long lda, long sA,
    const unsigned short* __restrict__ BT, long ldb, long sB,
    void* __restrict__ Cp, long ldc, long sC,
    const float* __restrict__ bias, float* __restrict__ aux) {
    constexpr int SPR = KK / 8;
    constexpr int RPI = 64 / SPR;
    __shared__ unsigned short As[128 * KK];
    __shared__ unsigned short Bs[128 * KK];
    const int tid  = threadIdx.x;
    const int lane = tid & 63;
    const int wave = tid >> 6;
    const int wr = (wave >> 1) * 64, wc = (wave & 1) * 64;
    const int l15 = lane & 15, lh = lane >> 4;
    const int sl  = lane & (SPR - 1);
    const int rof = lane / SPR;
    const int z = blockIdx.z;
    const unsigned short* Ab = A  + (size_t)z * sA + (size_t)blockIdx.y * 128 * lda;
    const unsigned short* Bb = BT + (size_t)z * sB + (size_t)blockIdx.x * 128 * ldb;

    f32x4 acc[4][4];
    #pragma unroll
    for (int i = 0; i < 4; ++i)
        #pragma unroll
        for (int j = 0; j < 4; ++j) { f32x4 zr = {0.f, 0.f, 0.f, 0.f}; acc[i][j] = zr; }

    #pragma unroll
    for (int i = 0; i < KK / 16; ++i) {
        int r0  = wave * 32 + i * RPI;
        int row = r0 + rof;
        int cs  = (sl ^ (row & (SPR - 1))) * 8;
        gl_lds16(Ab + (size_t)row * lda + cs, &As[r0 * KK]);
        gl_lds16(Bb + (size_t)row * ldb + cs, &Bs[r0 * KK]);
    }
    __syncthreads();

    #pragma unroll
    for (int ks = 0; ks < KK / 32; ++ks) {
        bf16x8 a[4], b[4];
        #pragma unroll
        for (int f = 0; f < 4; ++f) {
            int ra = wr + f * 16 + l15;
            a[f] = *(const bf16x8*)&As[ra * KK + ((((ks << 2) + lh) ^ (ra & (SPR - 1))) << 3)];
            int rb = wc + f * 16 + l15;
            b[f] = *(const bf16x8*)&Bs[rb * KK + ((((ks << 2) + lh) ^ (rb & (SPR - 1))) << 3)];
        }
        #pragma unroll
        for (int i = 0; i < 4; ++i)
            #pragma unroll
            for (int j = 0; j < 4; ++j)
                acc[i][j] = __builtin_amdgcn_mfma_f32_16x16x32_bf16(
                    a[i], b[j], acc[i][j], 0, 0, 0);
    }

    const int row0 = blockIdx.y * 128 + wr;
    const int col0 = blockIdx.x * 128 + wc;
    unsigned short* OUT = (unsigned short*)Cp + (size_t)z * sC;
    #pragma unroll
    for (int i = 0; i < 4; ++i)
        #pragma unroll
        for (int j = 0; j < 4; ++j) {
            int cgl = col0 + j * 16 + l15;
            float bc = (EPI == 1 || EPI == 2) ? bias[cgl] : 0.f;
            float sc = (EPI == 3) ? aux[(size_t)z * 4096 + cgl] : 1.f;
            #pragma unroll
            for (int q = 0; q < 4; ++q) {
                int r = row0 + i * 16 + lh * 4 + q;
                float v = acc[i][j][q];
                if (EPI == 3) v = (v + bias[r]) * sc;
                else v += bc;
                if (EPI == 1) v = fmaxf(v, 0.f);
                OUT[(size_t)r * ldc + cgl] = f2bf(v);
            }
        }
}

// ---------------------------------------------------------------------------
// 128x128-tile GEMM, 4 waves, BK=64 dbuf, counted-vmcnt loop (verified R13).
// EPI 0: S — store bf16(exp(acc)) + column-sum partials -> aux
// EPI 4: PV — splits==1 direct: alpha*CV+beta*acc (K=4096, T=64 deep loop)
// ---------------------------------------------------------------------------
template<int EPI>
__global__ __launch_bounds__(256) void gemm128(
    const unsigned short* __restrict__ A, long lda, long sA,
    const unsigned short* __restrict__ BT, long ldb, long sB,
    int Kc, int splits, int nb,
    void* __restrict__ Cp, long ldc, long sC,
    float* __restrict__ aux, unsigned short* __restrict__ partial,
    const unsigned short* __restrict__ CV,
    const float* __restrict__ alphaP, const float* __restrict__ betaP,
    int nwgc) {
    __shared__ unsigned short As[2][128 * 64];
    __shared__ unsigned short Bs[2][128 * 64];
    const int orig = blockIdx.x;
    const int wgid = (orig & 7) * nwgc + (orig >> 3);    // XCD-chunked, bijective
    int bx, by, sp, z;
    if (EPI == 0) {
        bx = wgid & 31; by = (wgid >> 5) & 31; z = wgid >> 10; sp = 0;
    } else {
        bx = wgid & 31; by = (wgid >> 5) & 1;            // by = c-half
        sp = (wgid >> 6) % splits; z = wgid / (64 * splits);
    }

    const int tid  = threadIdx.x;
    const int lane = tid & 63;
    const int wave = tid >> 6;
    const int wr = (wave >> 1) * 64, wc = (wave & 1) * 64;
    const int l15 = lane & 15, lh = lane >> 4;
    const int sl  = lane & 7, rof = lane >> 3;
    const unsigned short* Ab = A  + (size_t)z * sA + (size_t)by * 128 * lda + (size_t)sp * Kc;
    const unsigned short* Bb = BT + (size_t)z * sB + (size_t)bx * 128 * ldb + (size_t)sp * Kc;

    f32x4 acc[4][4];
    #pragma unroll
    for (int i = 0; i < 4; ++i)
        #pragma unroll
        for (int j = 0; j < 4; ++j) { f32x4 zr = {0.f, 0.f, 0.f, 0.f}; acc[i][j] = zr; }

    auto STAGE = [&](int buf, int k0) {       // 8 gl_lds per wave (4 A + 4 B)
        #pragma unroll
        for (int s = 0; s < 4; ++s) {
            int rb  = wave * 8 + s * 32;
            int row = rb + rof;
            int cs  = (sl ^ (row & 7)) * 8;
            gl_lds16(Ab + (size_t)row * lda + k0 + cs, &As[buf][rb * 64]);
            gl_lds16(Bb + (size_t)row * ldb + k0 + cs, &Bs[buf][rb * 64]);
        }
    };

    STAGE(0, 0);
    const int T = Kc >> 6;
    for (int t = 0; t < T; ++t) {
        const int cur = t & 1;
        if (t + 1 < T) {
            STAGE(cur ^ 1, (t + 1) << 6);     // next tile stays in flight
            asm volatile("s_waitcnt vmcnt(8)" ::: "memory");   // tile t landed
        } else {
            asm volatile("s_waitcnt vmcnt(0)" ::: "memory");
        }
        __builtin_amdgcn_s_barrier();
        asm volatile("" ::: "memory");
        __builtin_amdgcn_s_setprio(1);
        #pragma unroll
        for (int ks = 0; ks < 2; ++ks) {
            bf16x8 a[4], b[4];
            #pragma unroll
            for (int f = 0; f < 4; ++f) {
                int ra = wr + f * 16 + l15;
                a[f] = *(const bf16x8*)&As[cur][ra * 64 + ((((ks << 2) + lh) ^ (ra & 7)) << 3)];
                int rb = wc + f * 16 + l15;
                b[f] = *(const bf16x8*)&Bs[cur][rb * 64 + ((((ks << 2) + lh) ^ (rb & 7)) << 3)];
            }
            #pragma unroll
            for (int i = 0; i < 4; ++i)
                #pragma unroll
                for (int j = 0; j < 4; ++j)
                    acc[i][j] = __builtin_amdgcn_mfma_f32_16x16x32_bf16(
                        a[i], b[j], acc[i][j], 0, 0, 0);
        }
        __builtin_amdgcn_s_setprio(0);
        asm volatile("" ::: "memory");
        __builtin_amdgcn_s_barrier();
    }

    if (EPI == 0) {
        unsigned short* OUT = (unsigned short*)Cp + (size_t)z * sC;
        const int row0 = by * 128 + wr;
        const int col0 = bx * 128 + wc;
        float cs4[4] = {0.f, 0.f, 0.f, 0.f};
        #pragma unroll
        for (int i = 0; i < 4; ++i)
            #pragma unroll
            for (int j = 0; j < 4; ++j) {
                int cgl = col0 + j * 16 + l15;
                #pragma unroll
                for (int q = 0; q < 4; ++q) {
                    int r = row0 + i * 16 + lh * 4 + q;
                    unsigned short h = f2bf(__expf(acc[i][j][q]));
                    OUT[(size_t)r * ldc + cgl] = h;
                    cs4[j] += bf2f(h);          // sum the ROUNDED numerator
                }
            }
        #pragma unroll
        for (int off = 16; off <= 32; off <<= 1)    // reduce over lh (rows)
            #pragma unroll
            for (int j = 0; j < 4; ++j)
                cs4[j] += __shfl_xor(cs4[j], off);
        if (lh == 0) {
            float* part = aux + (((size_t)z * 32 + by) * 2 + (wave >> 1)) * 4096;
            #pragma unroll
            for (int j = 0; j < 4; ++j)
                part[col0 + j * 16 + l15] = cs4[j];
        }
    } else {
        const int col0 = bx * 128 + wc;
        const int row0 = by * 128 + wr;
        float* OUT = (float*)Cp + (size_t)z * sC;
        const unsigned short* CVb = CV + (size_t)z * sC;
        const float al = alphaP[0], be = betaP[0];
        #pragma unroll
        for (int i = 0; i < 4; ++i)
            #pragma unroll
            for (int j = 0; j < 4; ++j) {
                int cgl = col0 + j * 16 + l15;
                #pragma unroll
                for (int q = 0; q < 4; ++q) {
                    int r = row0 + i * 16 + lh * 4 + q;
                    size_t o = (size_t)r * ldc + cgl;
                    OUT[o] = al * bf2f(CVb[o]) + be * acc[i][j][q];
                }
            }
    }
}

// ---------------------------------------------------------------------------
// rcp[z][n] = 1 / sum over 64 partials (32 row-blocks x 2 halves)
// ---------------------------------------------------------------------------
__global__ __launch_bounds__(256) void recip_kernel(
    const float* __restrict__ part, float* __restrict__ rcp) {
    int idx = blockIdx.x * 256 + threadIdx.x;
    int z = idx >> 12, n = idx & 4095;
    const float* pb = part + (size_t)z * 64 * 4096 + n;
    float s = 0.f;
    #pragma unroll 8
    for (int t = 0; t < 64; ++t) s += pb[(size_t)t * 4096];
    rcp[idx] = 1.f / s;
}

// ---------------------------------------------------------------------------
// 3x3 SAME conv v4: 64-o x 128-px blocks; WEIGHT staging now async gl_lds
// into linear wt[9*64][32] (tap-aligned 16-row groups; 2-way banks = free).
// Patch staging stays VGPR (needs OOB zero-fill). 58 KB LDS -> 2 blocks/CU.
// ---------------------------------------------------------------------------
template<int PIXOUT>
__global__ __launch_bounds__(256) void conv3_v4(
    const unsigned short* __restrict__ X, const unsigned short* __restrict__ Wr,
    const float* __restrict__ bias, void* __restrict__ Outp) {
    __shared__ unsigned short wt[9 * 64 * 32];   // [tap*64+o][32c] linear
    __shared__ unsigned short patch[264 * 40];
    const int tid  = threadIdx.x;
    const int lane = tid & 63;
    const int wave = tid >> 6;
    const int l15 = lane & 15, lh = lane >> 4;
    const int ob = blockIdx.x & 3;              // 64-o block (0..3)
    const int b  = blockIdx.x >> 2;
    const int h0 = blockIdx.y;
    const int obase = (wave & 1) * 32;
    const int pbase = (wave >> 1) * 64;
    const unsigned short* Xb  = X + (size_t)b * (NPIX * CC);
    const unsigned short* Wro = Wr + (size_t)ob * 64 * 2304;
    // per-lane weight-staging global base: o = wave*16 + (lane>>2), 16B slot
    const size_t wgbase = (size_t)(wave * 16 + (lane >> 2)) * 2304 + (lane & 3) * 8;

    constexpr int NI = PIXOUT ? 4 : 2;
    constexpr int NJ = PIXOUT ? 2 : 4;
    f32x4 acc[NI][NJ];
    #pragma unroll
    for (int i = 0; i < NI; ++i)
        #pragma unroll
        for (int j = 0; j < NJ; ++j) { f32x4 zr = {0.f, 0.f, 0.f, 0.f}; acc[i][j] = zr; }

    for (int c0 = 0; c0 < 256; c0 += 32) {
        __syncthreads();                        // previous chunk's reads done
        // async weight stage: 9 taps x 64 o x 32 c, 9 gl_lds per wave
        #pragma unroll
        for (int s = 0; s < 9; ++s)
            gl_lds16(Wro + wgbase + s * 256 + c0, &wt[(s * 64 + wave * 16) * 32]);
        // patch stage via VGPR (zero halo): 1056 int4
        #pragma unroll
        for (int t = 0; t < 5; ++t) {
            int q = t * 256 + tid;
            if (q < 1056) {
                int slot = q >> 2, cg = (q & 3) * 8;
                int r = slot / 66, w = slot - r * 66;
                int hh = h0 * 2 - 1 + r, ww = w - 1;
                int4 v = make_int4(0, 0, 0, 0);
                if ((unsigned)hh < 64u && (unsigned)ww < 64u)
                    v = *(const int4*)&Xb[(size_t)(hh * 64 + ww) * 256 + c0 + cg];
                *(int4*)&patch[slot * 40 + cg] = v;
            }
        }
        __syncthreads();                        // drains vmcnt+lgkmcnt
        #pragma unroll
        for (int tap = 0; tap < 9; ++tap) {
            const int dy = tap / 3 - 1, dx = tap % 3 - 1;
            bf16x8 wf[2], pf[4];
            #pragma unroll
            for (int f = 0; f < 2; ++f) {
                int o = obase + f * 16 + l15;
                wf[f] = *(const bf16x8*)&wt[(tap * 64 + o) * 32 + lh * 8];
            }
            #pragma unroll
            for (int f = 0; f < 4; ++f) {
                int p = pbase + f * 16 + l15;
                int slot = ((p >> 6) + dy + 1) * 66 + (p & 63) + dx + 1;
                pf[f] = *(const bf16x8*)&patch[slot * 40 + lh * 8];
            }
            if (PIXOUT) {
                #pragma unroll
                for (int i = 0; i < NI; ++i)
                    #pragma unroll
                    for (int j = 0; j < NJ; ++j)
                        acc[i][j] = __builtin_amdgcn_mfma_f32_16x16x32_bf16(
                            pf[i], wf[j], acc[i][j], 0, 0, 0);
            } else {
                #pragma unroll
                for (int i = 0; i < NI; ++i)
                    #pragma unroll
                    for (int j = 0; j < NJ; ++j)
                        acc[i][j] = __builtin_amdgcn_mfma_f32_16x16x32_bf16(
                            wf[i], pf[j], acc[i][j], 0, 0, 0);
            }
        }
    }

    const int P0 = h0 * 128;
    if (PIXOUT) {
        unsigned short* O = (unsigned short*)Outp + (size_t)b * (NPIX * CC);
        #pragma unroll
        for (int i = 0; i < 4; ++i)
            #pragma unroll
            for (int j = 0; j < 2; ++j) {
                int o = ob * 64 + obase + j * 16 + l15;
                float bb = bias[o];
                #pragma unroll
                for (int q = 0; q < 4; ++q) {
                    int p = pbase + i * 16 + lh * 4 + q;
                    float v = fmaxf(acc[i][j][q] + bb, 0.f);
                    O[(size_t)(P0 + p) * CC + o] = f2bf(v);
                }
            }
    } else {
        unsigned short* O = (unsigned short*)Outp + (size_t)b * (CC * NPIX);
        #pragma unroll
        for (int i = 0; i < 2; ++i)
            #pragma unroll
            for (int j = 0; j < 4; ++j) {
                #pragma unroll
                for (int q = 0; q < 4; ++q) {
                    int o = ob * 64 + obase + i * 16 + lh * 4 + q;
                    int p = pbase + j * 16 + l15;
                    O[(size_t)o * NPIX + P0 + p] = f2bf(acc[i][j][q] + bias[o]);
                }
            }
    }
}

// ---------------------------------------------------------------------------
extern "C" void kernel_launch(void* const* d_in, const int* in_sizes, int n_in,
                              void* d_out, int out_size, void* d_ws, size_t ws_size,
                              hipStream_t stream) {
    const float* x   = (const float*)d_in[0];
    const float* w1  = (const float*)d_in[1];  const float* b1  = (const float*)d_in[2];
    const float* w2  = (const float*)d_in[3];  const float* b2  = (const float*)d_in[4];
    const float* w3  = (const float*)d_in[5];  const float* b3  = (const float*)d_in[6];
    const float* wb1 = (const float*)d_in[7];  const float* bb1 = (const float*)d_in[8];
    const float* wb2 = (const float*)d_in[9];  const float* bb2 = (const float*)d_in[10];
    const float* wq  = (const float*)d_in[11]; const float* bq  = (const float*)d_in[12];
    const float* wk  = (const float*)d_in[13]; const float* bk  = (const float*)d_in[14];
    const float* wv  = (const float*)d_in[15]; const float* bv  = (const float*)d_in[16];
    const float* alpha = (const float*)d_in[17];
    const float* beta  = (const float*)d_in[18];

    const size_t MB = 1 << 20;
    char* wsb = (char*)d_ws;
    unsigned short* x3T = (unsigned short*)(wsb + 0 * MB);   // [4][4096][256]
    unsigned short* qkT = (unsigned short*)(wsb + 8 * MB);   // [4][4096][512]
    unsigned short* cv  = (unsigned short*)(wsb + 24 * MB);  // [4][256][4096] bf16
    unsigned short* t1T = (unsigned short*)(wsb + 32 * MB);  // [4][4096][256]
    unsigned short* h1T = (unsigned short*)(wsb + 32 * MB);  // overlay
    unsigned short* h2T = (unsigned short*)(wsb + 34 * MB);  // overlay
    unsigned short* vB  = (unsigned short*)(wsb + 40 * MB);  // [nb][256][4096] bf16
    unsigned short* w2b = (unsigned short*)(wsb + 48 * MB);
    unsigned short* w3b = w2b + 8192;
    unsigned short* wqb = w3b + 32768;
    unsigned short* wkb = wqb + 65536;
    unsigned short* wvb = wkb + 65536;
    unsigned short* wr1 = wvb + 65536;
    unsigned short* wr2 = wr1 + 589824;
    float*          bqk  = (float*)(wsb + 51 * MB);
    float*          part = (float*)(wsb + 52 * MB);          // [4][32][2][4096] f32
    float*          rcp  = (float*)(wsb + 56 * MB);          // [4][4096]
    unsigned short* ST   = (unsigned short*)(wsb + 57 * MB); // [nb][4096][4096] bf16
    float* out = (float*)d_out;
    const long ONEM = (long)CC * NPIX;
    const long SS = 4096L * 4096;

    // gates: 57 + nb*32 (ST) MB  (no PV partials anymore — splits always 1)
    int nb;
    if      (ws_size >= (size_t)185 * MB) nb = 4;
    else if (ws_size >= (size_t)121 * MB) nb = 2;
    else                                  nb = 1;

    prep_kernel<<<2304, 256, 0, stream>>>(w2, w3, wq, wk, wv, wb1, wb2, bq, bk,
                                          w2b, w3b, wqb, wkb, wvb, wr1, wr2, bqk);
    stem1_kernel<<<4096, 256, 0, stream>>>(x, w1, b1, h1T);

    gemm_fullk<1, 64><<<dim3(1, 32, 4), 256, 0, stream>>>(
        h1T, 64, 4096L * 64, w2b, 64, 0,
        h2T, 128, 4096L * 128, b2, nullptr);
    gemm_fullk<1, 128><<<dim3(2, 32, 4), 256, 0, stream>>>(
        h2T, 128, 4096L * 128, w3b, 128, 0,
        x3T, 256, 4096L * 256, b3, nullptr);
    gemm_fullk<2, 256><<<dim3(4, 32, 4), 256, 0, stream>>>(
        x3T, 256, 4096L * 256, wqb, 256, 0,
        qkT, 512, 4096L * 512, bqk, nullptr);
    conv3_v4<1><<<dim3(16, 32), 256, 0, stream>>>(x3T, wr1, bb1, t1T);
    conv3_v4<0><<<dim3(16, 32), 256, 0, stream>>>(t1T, wr2, bb2, cv);

    for (int b0 = 0; b0 < 4; b0 += nb) {
        // S: EST = bf16(exp(Q.K^T)) + column partials — 128^2
        int nwgS = 1024 * nb;
        gemm128<0><<<nwgS, 256, 0, stream>>>(
            qkT + (size_t)b0 * 4096 * 512, 512, 4096L * 512,
            qkT + (size_t)b0 * 4096 * 512 + 256, 512, 4096L * 512,
            256, 1, nb, ST, 4096, SS,
            part, nullptr, nullptr, nullptr, nullptr, nwgS / 8);
        recip_kernel<<<nb * 16, 256, 0, stream>>>(part, rcp);
        // V' = (Wv x3 + bv) * rcp[n]
        gemm_fullk<3, 256><<<dim3(32, 2, nb), 256, 0, stream>>>(
            wvb, 256, 0,
            x3T + (size_t)b0 * 4096 * 256, 256, 4096L * 256,
            vB, 4096, 256L * 4096, bv, rcp);
        // PV: direct write (splits=1), K=4096 deep loop
        int nwgP = 64 * nb;
        gemm128<4><<<nwgP, 256, 0, stream>>>(
            vB, 4096, 256L * 4096, ST, 4096, SS,
            4096, 1, nb,
            out + (size_t)b0 * ONEM, 4096, ONEM,
            nullptr, nullptr, cv + (size_t)b0 * ONEM, alpha, beta, nwgP / 8);
    }
}

// Round 15
// 208.995 us; speedup vs baseline: 3.2043x; 1.1437x over previous
//
#include <hip/hip_runtime.h>
#include <math.h>

#define NPIX 4096
#define CC   256

typedef __attribute__((ext_vector_type(8))) short bf16x8;
typedef __attribute__((ext_vector_type(4))) float f32x4;

__device__ inline unsigned short f2bf(float f) {
    unsigned u = __builtin_bit_cast(unsigned, f);
    u += 0x7FFF + ((u >> 16) & 1);              // RTN-E
    return (unsigned short)(u >> 16);
}
__device__ inline float bf2f(unsigned short h) {
    unsigned u = (unsigned)h << 16;
    return __builtin_bit_cast(float, u);
}
__device__ inline void gl_lds16(const void* g, void* l) {
    __builtin_amdgcn_global_load_lds(
        (const __attribute__((address_space(1))) void*)g,
        (__attribute__((address_space(3))) void*)l, 16, 0, 0);
}

// ---------------------------------------------------------------------------
// Weight prep (unchanged, verified)
// ---------------------------------------------------------------------------
__global__ __launch_bounds__(256) void prep_kernel(
    const float* __restrict__ w2, const float* __restrict__ w3,
    const float* __restrict__ wq, const float* __restrict__ wk,
    const float* __restrict__ wv, const float* __restrict__ wb1,
    const float* __restrict__ wb2, const float* __restrict__ bq,
    const float* __restrict__ bk,
    unsigned short* w2b, unsigned short* w3b, unsigned short* wqb,
    unsigned short* wkb, unsigned short* wvb,
    unsigned short* wr1, unsigned short* wr2, float* bqk) {
    int i = blockIdx.x * 256 + threadIdx.x;
    if (i < 8192)  w2b[i] = f2bf(w2[i]);
    if (i < 32768) w3b[i] = f2bf(w3[i]);
    if (i < 65536) { wqb[i] = f2bf(wq[i]); wkb[i] = f2bf(wk[i]); wvb[i] = f2bf(wv[i]); }
    if (i < 256)   { bqk[i] = bq[i]; bqk[256 + i] = bk[i]; }
    if (i < 589824) {
        int o = i / 2304; int r = i - o * 2304; int tap = r >> 8; int c = r & 255;
        wr1[i] = f2bf(wb1[(o * 256 + c) * 9 + tap]);
        wr2[i] = f2bf(wb2[(o * 256 + c) * 9 + tap]);
    }
}

// ---------------------------------------------------------------------------
// Stem (unchanged, verified)
// ---------------------------------------------------------------------------
__global__ __launch_bounds__(256) void stem1_kernel(
    const float* __restrict__ x, const float* __restrict__ w1,
    const float* __restrict__ b1, unsigned short* __restrict__ h1T) {
    int idx = blockIdx.x * 256 + threadIdx.x;
    int o = idx & 63;
    int p = (idx >> 6) & 4095;
    int b = idx >> 18;
    const float* xb = x + (size_t)b * 3 * NPIX + p;
    float acc = b1[o];
    acc = fmaf(w1[o * 3 + 0], xb[0],        acc);
    acc = fmaf(w1[o * 3 + 1], xb[NPIX],     acc);
    acc = fmaf(w1[o * 3 + 2], xb[2 * NPIX], acc);
    h1T[idx] = f2bf(fmaxf(acc, 0.f));
}

// ---------------------------------------------------------------------------
// Full-K single-stage GEMM (K<=256) — verified. conv2/conv3 1x1, q|k, V'.
// ---------------------------------------------------------------------------
template<int EPI, int KK>
__global__ __launch_bounds__(256) void gemm_fullk(
    const unsigned short* __restrict__ A, long lda, long sA,
    const unsigned short* __restrict__ BT, long ldb, long sB,
    void* __restrict__ Cp, long ldc, long sC,
    const float* __restrict__ bias, float* __restrict__ aux) {
    constexpr int SPR = KK / 8;
    constexpr int RPI = 64 / SPR;
    __shared__ unsigned short As[128 * KK];
    __shared__ unsigned short Bs[128 * KK];
    const int tid  = threadIdx.x;
    const int lane = tid & 63;
    const int wave = tid >> 6;
    const int wr = (wave >> 1) * 64, wc = (wave & 1) * 64;
    const int l15 = lane & 15, lh = lane >> 4;
    const int sl  = lane & (SPR - 1);
    const int rof = lane / SPR;
    const int z = blockIdx.z;
    const unsigned short* Ab = A  + (size_t)z * sA + (size_t)blockIdx.y * 128 * lda;
    const unsigned short* Bb = BT + (size_t)z * sB + (size_t)blockIdx.x * 128 * ldb;

    f32x4 acc[4][4];
    #pragma unroll
    for (int i = 0; i < 4; ++i)
        #pragma unroll
        for (int j = 0; j < 4; ++j) { f32x4 zr = {0.f, 0.f, 0.f, 0.f}; acc[i][j] = zr; }

    #pragma unroll
    for (int i = 0; i < KK / 16; ++i) {
        int r0  = wave * 32 + i * RPI;
        int row = r0 + rof;
        int cs  = (sl ^ (row & (SPR - 1))) * 8;
        gl_lds16(Ab + (size_t)row * lda + cs, &As[r0 * KK]);
        gl_lds16(Bb + (size_t)row * ldb + cs, &Bs[r0 * KK]);
    }
    __syncthreads();

    #pragma unroll
    for (int ks = 0; ks < KK / 32; ++ks) {
        bf16x8 a[4], b[4];
        #pragma unroll
        for (int f = 0; f < 4; ++f) {
            int ra = wr + f * 16 + l15;
            a[f] = *(const bf16x8*)&As[ra * KK + ((((ks << 2) + lh) ^ (ra & (SPR - 1))) << 3)];
            int rb = wc + f * 16 + l15;
            b[f] = *(const bf16x8*)&Bs[rb * KK + ((((ks << 2) + lh) ^ (rb & (SPR - 1))) << 3)];
        }
        #pragma unroll
        for (int i = 0; i < 4; ++i)
            #pragma unroll
            for (int j = 0; j < 4; ++j)
                acc[i][j] = __builtin_amdgcn_mfma_f32_16x16x32_bf16(
                    a[i], b[j], acc[i][j], 0, 0, 0);
    }

    const int row0 = blockIdx.y * 128 + wr;
    const int col0 = blockIdx.x * 128 + wc;
    unsigned short* OUT = (unsigned short*)Cp + (size_t)z * sC;
    #pragma unroll
    for (int i = 0; i < 4; ++i)
        #pragma unroll
        for (int j = 0; j < 4; ++j) {
            int cgl = col0 + j * 16 + l15;
            float bc = (EPI == 1 || EPI == 2) ? bias[cgl] : 0.f;
            float sc = (EPI == 3) ? aux[(size_t)z * 4096 + cgl] : 1.f;
            #pragma unroll
            for (int q = 0; q < 4; ++q) {
                int r = row0 + i * 16 + lh * 4 + q;
                float v = acc[i][j][q];
                if (EPI == 3) v = (v + bias[r]) * sc;
                else v += bc;
                if (EPI == 1) v = fmaxf(v, 0.f);
                OUT[(size_t)r * ldc + cgl] = f2bf(v);
            }
        }
}

// ---------------------------------------------------------------------------
// 128x128-tile GEMM, *8 waves* (wave tile 64x32), BK=64 dbuf, counted-vmcnt
// loop (R8-verified structure). 64 KB LDS -> 2 blocks/CU -> 16 waves/CU, and
// 2x the in-flight gl_lds per CU (the R14 lesson: PV was request-starved at
// 4 waves/block, 1.9 TB/s fetch with all pipes idle).
// EPI 0: S — store bf16(exp(acc)) + column-sum partials -> aux
// EPI 4: PV — splits>1: bf16 partials; splits==1: alpha*CV+beta*acc direct
// ---------------------------------------------------------------------------
template<int EPI>
__global__ __launch_bounds__(512) void gemm128(
    const unsigned short* __restrict__ A, long lda, long sA,
    const unsigned short* __restrict__ BT, long ldb, long sB,
    int Kc, int splits, int nb,
    void* __restrict__ Cp, long ldc, long sC,
    float* __restrict__ aux, unsigned short* __restrict__ partial,
    const unsigned short* __restrict__ CV,
    const float* __restrict__ alphaP, const float* __restrict__ betaP,
    int nwgc) {
    __shared__ unsigned short As[2][128 * 64];
    __shared__ unsigned short Bs[2][128 * 64];
    const int orig = blockIdx.x;
    const int wgid = (orig & 7) * nwgc + (orig >> 3);    // XCD-chunked, bijective
    int bx, by, sp, z;
    if (EPI == 0) {
        bx = wgid & 31; by = (wgid >> 5) & 31; z = wgid >> 10; sp = 0;
    } else {
        bx = wgid & 31; by = (wgid >> 5) & 1;            // by = c-half
        sp = (wgid >> 6) % splits; z = wgid / (64 * splits);
    }

    const int tid  = threadIdx.x;
    const int lane = tid & 63;
    const int wave = tid >> 6;                  // 0..7
    const int wr = (wave >> 2) * 64;            // row half (64 rows)
    const int wc = (wave & 3) * 32;             // col quarter (32 cols)
    const int l15 = lane & 15, lh = lane >> 4;
    const int sl  = lane & 7, rof = lane >> 3;
    const unsigned short* Ab = A  + (size_t)z * sA + (size_t)by * 128 * lda + (size_t)sp * Kc;
    const unsigned short* Bb = BT + (size_t)z * sB + (size_t)bx * 128 * ldb + (size_t)sp * Kc;

    f32x4 acc[4][2];
    #pragma unroll
    for (int i = 0; i < 4; ++i)
        #pragma unroll
        for (int j = 0; j < 2; ++j) { f32x4 zr = {0.f, 0.f, 0.f, 0.f}; acc[i][j] = zr; }

    auto STAGE = [&](int buf, int k0) {       // 4 gl_lds per wave (2 A + 2 B)
        #pragma unroll
        for (int s = 0; s < 2; ++s) {
            int rb  = wave * 16 + s * 8;
            int row = rb + rof;
            int cs  = (sl ^ (row & 7)) * 8;
            gl_lds16(Ab + (size_t)row * lda + k0 + cs, &As[buf][rb * 64]);
            gl_lds16(Bb + (size_t)row * ldb + k0 + cs, &Bs[buf][rb * 64]);
        }
    };

    STAGE(0, 0);
    const int T = Kc >> 6;
    for (int t = 0; t < T; ++t) {
        const int cur = t & 1;
        if (t + 1 < T) {
            STAGE(cur ^ 1, (t + 1) << 6);     // next tile stays in flight
            asm volatile("s_waitcnt vmcnt(4)" ::: "memory");   // tile t landed
        } else {
            asm volatile("s_waitcnt vmcnt(0)" ::: "memory");
        }
        __builtin_amdgcn_s_barrier();
        asm volatile("" ::: "memory");
        __builtin_amdgcn_s_setprio(1);
        #pragma unroll
        for (int ks = 0; ks < 2; ++ks) {
            bf16x8 a[4], b[2];
            #pragma unroll
            for (int f = 0; f < 4; ++f) {
                int ra = wr + f * 16 + l15;
                a[f] = *(const bf16x8*)&As[cur][ra * 64 + ((((ks << 2) + lh) ^ (ra & 7)) << 3)];
            }
            #pragma unroll
            for (int f = 0; f < 2; ++f) {
                int rb = wc + f * 16 + l15;
                b[f] = *(const bf16x8*)&Bs[cur][rb * 64 + ((((ks << 2) + lh) ^ (rb & 7)) << 3)];
            }
            #pragma unroll
            for (int i = 0; i < 4; ++i)
                #pragma unroll
                for (int j = 0; j < 2; ++j)
                    acc[i][j] = __builtin_amdgcn_mfma_f32_16x16x32_bf16(
                        a[i], b[j], acc[i][j], 0, 0, 0);
        }
        __builtin_amdgcn_s_setprio(0);
        asm volatile("" ::: "memory");
        __builtin_amdgcn_s_barrier();
    }

    if (EPI == 0) {
        unsigned short* OUT = (unsigned short*)Cp + (size_t)z * sC;
        const int row0 = by * 128 + wr;
        const int col0 = bx * 128 + wc;
        float cs2[2] = {0.f, 0.f};
        #pragma unroll
        for (int i = 0; i < 4; ++i)
            #pragma unroll
            for (int j = 0; j < 2; ++j) {
                int cgl = col0 + j * 16 + l15;
                #pragma unroll
                for (int q = 0; q < 4; ++q) {
                    int r = row0 + i * 16 + lh * 4 + q;
                    unsigned short h = f2bf(__expf(acc[i][j][q]));
                    OUT[(size_t)r * ldc + cgl] = h;
                    cs2[j] += bf2f(h);          // sum the ROUNDED numerator
                }
            }
        #pragma unroll
        for (int off = 16; off <= 32; off <<= 1)    // reduce over lh (rows)
            #pragma unroll
            for (int j = 0; j < 2; ++j)
                cs2[j] += __shfl_xor(cs2[j], off);
        if (lh == 0) {
            // [z][by(32)][rowhalf(2)][4096]; col-quarters (wave&3) disjoint
            float* part = aux + (((size_t)z * 32 + by) * 2 + (wave >> 2)) * 4096;
            #pragma unroll
            for (int j = 0; j < 2; ++j)
                part[col0 + j * 16 + l15] = cs2[j];
        }
    } else {
        const int col0 = bx * 128 + wc;
        const int row0 = by * 128 + wr;
        if (splits == 1) {
            float* OUT = (float*)Cp + (size_t)z * sC;
            const unsigned short* CVb = CV + (size_t)z * sC;
            const float al = alphaP[0], be = betaP[0];
            #pragma unroll
            for (int i = 0; i < 4; ++i)
                #pragma unroll
                for (int j = 0; j < 2; ++j) {
                    int cgl = col0 + j * 16 + l15;
                    #pragma unroll
                    for (int q = 0; q < 4; ++q) {
                        int r = row0 + i * 16 + lh * 4 + q;
                        size_t o = (size_t)r * ldc + cgl;
                        OUT[o] = al * bf2f(CVb[o]) + be * acc[i][j][q];
                    }
                }
        } else {
            unsigned short* P = partial + ((size_t)sp * nb + z) * ((size_t)256 * 4096);
            #pragma unroll
            for (int i = 0; i < 4; ++i)
                #pragma unroll
                for (int j = 0; j < 2; ++j) {
                    int cgl = col0 + j * 16 + l15;
                    #pragma unroll
                    for (int q = 0; q < 4; ++q) {
                        int r = row0 + i * 16 + lh * 4 + q;
                        P[(size_t)r * 4096 + cgl] = f2bf(acc[i][j][q]);
                    }
                }
        }
    }
}

// ---------------------------------------------------------------------------
// reduce: out = alpha*cv + beta * sum_sp bf16partial[sp]
// ---------------------------------------------------------------------------
__global__ __launch_bounds__(256) void reduce_kernel(
    const unsigned short* __restrict__ partial, const unsigned short* __restrict__ cvb,
    const float* __restrict__ alphaP, const float* __restrict__ betaP,
    float* __restrict__ outp, int splits, long chunk) {
    long idx = ((long)blockIdx.x * 256 + threadIdx.x) * 4;
    if (idx >= chunk) return;
    float s0 = 0.f, s1 = 0.f, s2 = 0.f, s3 = 0.f;
    for (int sp = 0; sp < splits; ++sp) {
        ushort4 p = *(const ushort4*)&partial[(size_t)sp * chunk + idx];
        s0 += bf2f(p.x); s1 += bf2f(p.y); s2 += bf2f(p.z); s3 += bf2f(p.w);
    }
    ushort4 c4 = *(const ushort4*)&cvb[idx];
    const float al = alphaP[0], be = betaP[0];
    float4 r;
    r.x = al * bf2f(c4.x) + be * s0;
    r.y = al * bf2f(c4.y) + be * s1;
    r.z = al * bf2f(c4.z) + be * s2;
    r.w = al * bf2f(c4.w) + be * s3;
    *(float4*)&outp[idx] = r;
}

// ---------------------------------------------------------------------------
// rcp[z][n] = 1 / sum over 64 partials (32 row-blocks x 2 halves)
// ---------------------------------------------------------------------------
__global__ __launch_bounds__(256) void recip_kernel(
    const float* __restrict__ part, float* __restrict__ rcp) {
    int idx = blockIdx.x * 256 + threadIdx.x;
    int z = idx >> 12, n = idx & 4095;
    const float* pb = part + (size_t)z * 64 * 4096 + n;
    float s = 0.f;
    #pragma unroll 8
    for (int t = 0; t < 64; ++t) s += pb[(size_t)t * 4096];
    rcp[idx] = 1.f / s;
}

// ---------------------------------------------------------------------------
// 3x3 SAME conv v4 (verified R14): async weight staging, 58 KB LDS.
// ---------------------------------------------------------------------------
template<int PIXOUT>
__global__ __launch_bounds__(256) void conv3_v4(
    const unsigned short* __restrict__ X, const unsigned short* __restrict__ Wr,
    const float* __restrict__ bias, void* __restrict__ Outp) {
    __shared__ unsigned short wt[9 * 64 * 32];   // [tap*64+o][32c] linear
    __shared__ unsigned short patch[264 * 40];
    const int tid  = threadIdx.x;
    const int lane = tid & 63;
    const int wave = tid >> 6;
    const int l15 = lane & 15, lh = lane >> 4;
    const int ob = blockIdx.x & 3;
    const int b  = blockIdx.x >> 2;
    const int h0 = blockIdx.y;
    const int obase = (wave & 1) * 32;
    const int pbase = (wave >> 1) * 64;
    const unsigned short* Xb  = X + (size_t)b * (NPIX * CC);
    const unsigned short* Wro = Wr + (size_t)ob * 64 * 2304;
    const size_t wgbase = (size_t)(wave * 16 + (lane >> 2)) * 2304 + (lane & 3) * 8;

    constexpr int NI = PIXOUT ? 4 : 2;
    constexpr int NJ = PIXOUT ? 2 : 4;
    f32x4 acc[NI][NJ];
    #pragma unroll
    for (int i = 0; i < NI; ++i)
        #pragma unroll
        for (int j = 0; j < NJ; ++j) { f32x4 zr = {0.f, 0.f, 0.f, 0.f}; acc[i][j] = zr; }

    for (int c0 = 0; c0 < 256; c0 += 32) {
        __syncthreads();
        #pragma unroll
        for (int s = 0; s < 9; ++s)
            gl_lds16(Wro + wgbase + s * 256 + c0, &wt[(s * 64 + wave * 16) * 32]);
        #pragma unroll
        for (int t = 0; t < 5; ++t) {
            int q = t * 256 + tid;
            if (q < 1056) {
                int slot = q >> 2, cg = (q & 3) * 8;
                int r = slot / 66, w = slot - r * 66;
                int hh = h0 * 2 - 1 + r, ww = w - 1;
                int4 v = make_int4(0, 0, 0, 0);
                if ((unsigned)hh < 64u && (unsigned)ww < 64u)
                    v = *(const int4*)&Xb[(size_t)(hh * 64 + ww) * 256 + c0 + cg];
                *(int4*)&patch[slot * 40 + cg] = v;
            }
        }
        __syncthreads();
        #pragma unroll
        for (int tap = 0; tap < 9; ++tap) {
            const int dy = tap / 3 - 1, dx = tap % 3 - 1;
            bf16x8 wf[2], pf[4];
            #pragma unroll
            for (int f = 0; f < 2; ++f) {
                int o = obase + f * 16 + l15;
                wf[f] = *(const bf16x8*)&wt[(tap * 64 + o) * 32 + lh * 8];
            }
            #pragma unroll
            for (int f = 0; f < 4; ++f) {
                int p = pbase + f * 16 + l15;
                int slot = ((p >> 6) + dy + 1) * 66 + (p & 63) + dx + 1;
                pf[f] = *(const bf16x8*)&patch[slot * 40 + lh * 8];
            }
            if (PIXOUT) {
                #pragma unroll
                for (int i = 0; i < NI; ++i)
                    #pragma unroll
                    for (int j = 0; j < NJ; ++j)
                        acc[i][j] = __builtin_amdgcn_mfma_f32_16x16x32_bf16(
                            pf[i], wf[j], acc[i][j], 0, 0, 0);
            } else {
                #pragma unroll
                for (int i = 0; i < NI; ++i)
                    #pragma unroll
                    for (int j = 0; j < NJ; ++j)
                        acc[i][j] = __builtin_amdgcn_mfma_f32_16x16x32_bf16(
                            wf[i], pf[j], acc[i][j], 0, 0, 0);
            }
        }
    }

    const int P0 = h0 * 128;
    if (PIXOUT) {
        unsigned short* O = (unsigned short*)Outp + (size_t)b * (NPIX * CC);
        #pragma unroll
        for (int i = 0; i < 4; ++i)
            #pragma unroll
            for (int j = 0; j < 2; ++j) {
                int o = ob * 64 + obase + j * 16 + l15;
                float bb = bias[o];
                #pragma unroll
                for (int q = 0; q < 4; ++q) {
                    int p = pbase + i * 16 + lh * 4 + q;
                    float v = fmaxf(acc[i][j][q] + bb, 0.f);
                    O[(size_t)(P0 + p) * CC + o] = f2bf(v);
                }
            }
    } else {
        unsigned short* O = (unsigned short*)Outp + (size_t)b * (CC * NPIX);
        #pragma unroll
        for (int i = 0; i < 2; ++i)
            #pragma unroll
            for (int j = 0; j < 4; ++j) {
                #pragma unroll
                for (int q = 0; q < 4; ++q) {
                    int o = ob * 64 + obase + i * 16 + lh * 4 + q;
                    int p = pbase + j * 16 + l15;
                    O[(size_t)o * NPIX + P0 + p] = f2bf(acc[i][j][q] + bias[o]);
                }
            }
    }
}

// ---------------------------------------------------------------------------
extern "C" void kernel_launch(void* const* d_in, const int* in_sizes, int n_in,
                              void* d_out, int out_size, void* d_ws, size_t ws_size,
                              hipStream_t stream) {
    const float* x   = (const float*)d_in[0];
    const float* w1  = (const float*)d_in[1];  const float* b1  = (const float*)d_in[2];
    const float* w2  = (const float*)d_in[3];  const float* b2  = (const float*)d_in[4];
    const float* w3  = (const float*)d_in[5];  const float* b3  = (const float*)d_in[6];
    const float* wb1 = (const float*)d_in[7];  const float* bb1 = (const float*)d_in[8];
    const float* wb2 = (const float*)d_in[9];  const float* bb2 = (const float*)d_in[10];
    const float* wq  = (const float*)d_in[11]; const float* bq  = (const float*)d_in[12];
    const float* wk  = (const float*)d_in[13]; const float* bk  = (const float*)d_in[14];
    const float* wv  = (const float*)d_in[15]; const float* bv  = (const float*)d_in[16];
    const float* alpha = (const float*)d_in[17];
    const float* beta  = (const float*)d_in[18];

    const size_t MB = 1 << 20;
    char* wsb = (char*)d_ws;
    unsigned short* x3T = (unsigned short*)(wsb + 0 * MB);   // [4][4096][256]
    unsigned short* qkT = (unsigned short*)(wsb + 8 * MB);   // [4][4096][512]
    unsigned short* cv  = (unsigned short*)(wsb + 24 * MB);  // [4][256][4096] bf16
    unsigned short* t1T = (unsigned short*)(wsb + 32 * MB);  // [4][4096][256]
    unsigned short* h1T = (unsigned short*)(wsb + 32 * MB);  // overlay
    unsigned short* h2T = (unsigned short*)(wsb + 34 * MB);  // overlay
    unsigned short* vB  = (unsigned short*)(wsb + 40 * MB);  // [nb][256][4096] bf16
    unsigned short* w2b = (unsigned short*)(wsb + 48 * MB);
    unsigned short* w3b = w2b + 8192;
    unsigned short* wqb = w3b + 32768;
    unsigned short* wkb = wqb + 65536;
    unsigned short* wvb = wkb + 65536;
    unsigned short* wr1 = wvb + 65536;
    unsigned short* wr2 = wr1 + 589824;
    float*          bqk  = (float*)(wsb + 51 * MB);
    float*          part = (float*)(wsb + 52 * MB);          // [4][32][2][4096] f32
    float*          rcp  = (float*)(wsb + 56 * MB);          // [4][4096]
    unsigned short* ST   = (unsigned short*)(wsb + 57 * MB); // [nb][4096][4096] bf16
    float* out = (float*)d_out;
    const long ONEM = (long)CC * NPIX;
    const long SS = 4096L * 4096;

    // gates: 57 + nb*32 (ST) + splits*nb*2 (bf16 partials) MB
    int nb, splits;
    if      (ws_size >= (size_t)201 * MB) { nb = 4; splits = 2; }
    else if (ws_size >= (size_t)185 * MB) { nb = 4; splits = 1; }
    else if (ws_size >= (size_t)129 * MB) { nb = 2; splits = 2; }
    else if (ws_size >= (size_t)121 * MB) { nb = 2; splits = 1; }
    else if (ws_size >= (size_t)93  * MB) { nb = 1; splits = 2; }
    else                                  { nb = 1; splits = 1; }
    unsigned short* pvpart = (unsigned short*)(wsb + (size_t)(57 + nb * 32) * MB);

    prep_kernel<<<2304, 256, 0, stream>>>(w2, w3, wq, wk, wv, wb1, wb2, bq, bk,
                                          w2b, w3b, wqb, wkb, wvb, wr1, wr2, bqk);
    stem1_kernel<<<4096, 256, 0, stream>>>(x, w1, b1, h1T);

    gemm_fullk<1, 64><<<dim3(1, 32, 4), 256, 0, stream>>>(
        h1T, 64, 4096L * 64, w2b, 64, 0,
        h2T, 128, 4096L * 128, b2, nullptr);
    gemm_fullk<1, 128><<<dim3(2, 32, 4), 256, 0, stream>>>(
        h2T, 128, 4096L * 128, w3b, 128, 0,
        x3T, 256, 4096L * 256, b3, nullptr);
    gemm_fullk<2, 256><<<dim3(4, 32, 4), 256, 0, stream>>>(
        x3T, 256, 4096L * 256, wqb, 256, 0,
        qkT, 512, 4096L * 512, bqk, nullptr);
    conv3_v4<1><<<dim3(16, 32), 256, 0, stream>>>(x3T, wr1, bb1, t1T);
    conv3_v4<0><<<dim3(16, 32), 256, 0, stream>>>(t1T, wr2, bb2, cv);

    for (int b0 = 0; b0 < 4; b0 += nb) {
        // S: EST = bf16(exp(Q.K^T)) + column partials — 8-wave 128^2
        int nwgS = 1024 * nb;
        gemm128<0><<<nwgS, 512, 0, stream>>>(
            qkT + (size_t)b0 * 4096 * 512, 512, 4096L * 512,
            qkT + (size_t)b0 * 4096 * 512 + 256, 512, 4096L * 512,
            256, 1, nb, ST, 4096, SS,
            part, nullptr, nullptr, nullptr, nullptr, nwgS / 8);
        recip_kernel<<<nb * 16, 256, 0, stream>>>(part, rcp);
        // V' = (Wv x3 + bv) * rcp[n]
        gemm_fullk<3, 256><<<dim3(32, 2, nb), 256, 0, stream>>>(
            wvb, 256, 0,
            x3T + (size_t)b0 * 4096 * 256, 256, 4096L * 256,
            vB, 4096, 256L * 4096, bv, rcp);
        // PV: 8-wave 128^2, split-K for grid >= 2 blocks/CU
        int nwgP = 64 * splits * nb;
        gemm128<4><<<nwgP, 512, 0, stream>>>(
            vB, 4096, 256L * 4096, ST, 4096, SS,
            4096 / splits, splits, nb,
            out + (size_t)b0 * ONEM, 4096, ONEM,
            nullptr, pvpart, cv + (size_t)b0 * ONEM, alpha, beta, nwgP / 8);
        if (splits > 1)
            reduce_kernel<<<nb * 1024, 256, 0, stream>>>(
                pvpart, cv + (size_t)b0 * ONEM, alpha, beta,
                out + (size_t)b0 * ONEM, splits, (long)nb * ONEM);
    }
}